// Round 1
// baseline (2120.920 us; speedup 1.0000x reference)
//
#include <hip/hip_runtime.h>

typedef __attribute__((ext_vector_type(8))) short short8;
typedef __attribute__((ext_vector_type(4))) float f32x4;

__device__ __forceinline__ unsigned short f2bf(float f) {
  unsigned int u = __float_as_uint(f);
  u += 0x7fffu + ((u >> 16) & 1u);   // RNE round to bf16
  return (unsigned short)(u >> 16);
}
__device__ __forceinline__ float sigm(float x) { return 1.f / (1.f + expf(-x)); }

// ---------------------------------------------------------------------------
// Generic skinny GEMM: C[(mbase+m)*N + n] (+ z*slotStride)
//   = sum_{k in chunk z} X_bf16[m][k] * W_f32[n][k]   (+ bias if given)
// X padded to multiples of 112 rows; 4 waves/block, each wave = 16 cols x 112 rows.
// ---------------------------------------------------------------------------
__global__ __launch_bounds__(256) void gemm_bt(
    const unsigned short* __restrict__ X, int ldx,
    const float* __restrict__ W, int ldw, int N,
    float* __restrict__ C, int Kchunk,
    const float* __restrict__ bias, long long slotStride)
{
  const int lane = threadIdx.x & 63;
  const int wv   = threadIdx.x >> 6;
  const int mbase = blockIdx.y * 112;
  const int l16 = lane & 15;
  const int kg  = (lane >> 4) * 8;
  const int ncol = blockIdx.x * 64 + wv * 16 + l16;
  const int nrow = (ncol < N) ? ncol : (N - 1);
  const int k0 = blockIdx.z * Kchunk;
  C += (long long)blockIdx.z * slotStride;

  const float* wp = W + (size_t)nrow * ldw + kg;
  const unsigned short* xp = X + (size_t)(mbase + l16) * ldx + kg;

  f32x4 acc[7];
#pragma unroll
  for (int i = 0; i < 7; ++i) acc[i] = (f32x4){0.f, 0.f, 0.f, 0.f};

  for (int k = k0; k < k0 + Kchunk; k += 32) {
    const float4 w0 = *(const float4*)(wp + k);
    const float4 w1 = *(const float4*)(wp + k + 4);
    short8 bfr;
    bfr[0] = (short)f2bf(w0.x); bfr[1] = (short)f2bf(w0.y);
    bfr[2] = (short)f2bf(w0.z); bfr[3] = (short)f2bf(w0.w);
    bfr[4] = (short)f2bf(w1.x); bfr[5] = (short)f2bf(w1.y);
    bfr[6] = (short)f2bf(w1.z); bfr[7] = (short)f2bf(w1.w);
#pragma unroll
    for (int mt = 0; mt < 7; ++mt) {
      short8 a = *(const short8*)(xp + (size_t)mt * 16 * ldx + k);
      acc[mt] = __builtin_amdgcn_mfma_f32_16x16x32_bf16(a, bfr, acc[mt], 0, 0, 0);
    }
  }
  if (ncol < N) {
    const float bv = bias ? bias[ncol] : 0.f;
    const int r0 = (lane >> 4) * 4;
#pragma unroll
    for (int mt = 0; mt < 7; ++mt)
#pragma unroll
      for (int r = 0; r < 4; ++r)
        C[(size_t)(mbase + mt * 16 + r0 + r) * N + ncol] = acc[mt][r] + bv;
  }
}

// --------------------------- phase-A helper kernels ------------------------
__global__ __launch_bounds__(256) void k_ximg(const float* __restrict__ src,
                                              unsigned short* __restrict__ dst) {
  int idx = blockIdx.x * 256 + threadIdx.x;          // 1568*4096
  int row = idx >> 12;
  dst[idx] = (row < 1500) ? f2bf(src[idx]) : (unsigned short)0;
}

__global__ __launch_bounds__(256) void k_mean(const float* __restrict__ img,
                                              unsigned short* __restrict__ dst) {
  int idx = blockIdx.x * 256 + threadIdx.x;          // 112*4096
  int b = idx >> 12, f = idx & 4095;
  unsigned short r = 0;
  if (b < 100) {
    float s = 0.f;
    for (int rr = 0; rr < 15; ++rr) s += img[((size_t)b * 15 + rr) * 4096 + f];
    r = f2bf(s * (1.f / 15.f));
  }
  dst[idx] = r;
}

__global__ __launch_bounds__(512) void k_conv(const float* __restrict__ lin,
    const float* __restrict__ cw, const float* __restrict__ cb,
    float* __restrict__ topics) {
  int b = blockIdx.x;
  __shared__ float L[15 * 1024];
  for (int i = threadIdx.x; i < 15 * 1024; i += 512) L[i] = lin[(size_t)b * 15360 + i];
  __syncthreads();
  for (int idx = threadIdx.x; idx < 2500; idx += 512) {
    int tt = idx / 500, w = idx - tt * 500;
    float s = cb[tt];
    for (int kh = 0; kh < 15; ++kh) {
      const float* lr = &L[kh * 1024 + 2 * w];
      const float* wr = &cw[(tt * 15 + kh) * 26];
#pragma unroll
      for (int kw = 0; kw < 26; ++kw) s += lr[kw] * wr[kw];
    }
    topics[(size_t)b * 2500 + idx] = s;
  }
}

__global__ __launch_bounds__(256) void k_ttop(const float* __restrict__ topics,
    const float* __restrict__ Wt, const float* __restrict__ btp,
    float* __restrict__ ttop) {
  int idx = blockIdx.x * 256 + threadIdx.x;          // 500*512
  int r = idx >> 9, n = idx & 511;
  const float4* tr = (const float4*)(topics + (size_t)r * 500);
  const float4* wr = (const float4*)(Wt + (size_t)n * 500);
  float s = btp[n];
  for (int k = 0; k < 125; ++k) {
    float4 a = tr[k], w = wr[k];
    s += a.x * w.x + a.y * w.y + a.z * w.z + a.w * w.w;
  }
  ttop[idx] = s;
}

__global__ void k_words(const int* __restrict__ caps, const int* __restrict__ lens,
                        int* __restrict__ words, float* __restrict__ out3) {
  int idx = blockIdx.x * 256 + threadIdx.x;
  if (idx >= 500) return;
  int len = lens[idx];
  words[idx] = caps[idx * 52 + len - 1];
  out3[idx] = (float)(len - 1);
}

__global__ void k_caps(const int* __restrict__ caps, float* __restrict__ out2) {
  int idx = blockIdx.x * 256 + threadIdx.x;
  if (idx < 26000) out2[idx] = (float)caps[idx];
}

__global__ __launch_bounds__(256) void k_gather(const float* __restrict__ emb,
    const int* __restrict__ words, unsigned short* __restrict__ Xemb) {
  int idx = blockIdx.x * 256 + threadIdx.x;          // 560*1024
  int bt = idx >> 10, e = idx & 1023;
  Xemb[idx] = (bt < 500) ? f2bf(emb[(size_t)words[bt] * 1024 + e]) : (unsigned short)0;
}

__global__ __launch_bounds__(256) void k_gbase1(const float* __restrict__ P,
    const float* __restrict__ bih, const float* __restrict__ bhh,
    float* __restrict__ gb) {
  int idx = blockIdx.x * 256 + threadIdx.x;          // 112*4096
  int m = idx >> 12, n = idx & 4095;
  float s = bih[n] + bhh[n];
#pragma unroll
  for (int sl = 0; sl < 8; ++sl) s += P[((size_t)sl * 112 + m) * 4096 + n];
  gb[idx] = s;
}

// ------------------------------ per-step kernels ---------------------------
__global__ __launch_bounds__(256) void k_lstm1(const float* __restrict__ P,
    const float* __restrict__ gb1, const float* __restrict__ gemb, int t,
    float* __restrict__ c1, unsigned short* __restrict__ Xh1,
    unsigned short* __restrict__ X1, unsigned short* __restrict__ X2) {
  int idx = blockIdx.x * 256 + threadIdx.x;          // 100*1024
  int b = idx >> 10, j = idx & 1023;
  float g[4];
#pragma unroll
  for (int x = 0; x < 4; ++x) {
    int col = (x << 10) + j;
    float s = gb1[b * 4096 + col] + gemb[((size_t)b * 5 + t) * 4096 + col];
#pragma unroll
    for (int sl = 0; sl < 8; ++sl) s += P[((size_t)sl * 112 + b) * 4096 + col];
    g[x] = s;
  }
  float c = sigm(g[1]) * c1[idx] + sigm(g[0]) * tanhf(g[2]);
  float h = sigm(g[3]) * tanhf(c);
  c1[idx] = c;
  unsigned short hb = f2bf(h);
  Xh1[idx] = hb;
  X1[b * 2048 + 1024 + j] = hb;
  X2[(size_t)b * 6144 + 4096 + j] = hb;
}

__global__ __launch_bounds__(256) void k_att(const float* __restrict__ att1,
    const float* __restrict__ padec, const float* __restrict__ bdec,
    const float* __restrict__ ttop, const float* __restrict__ wfull,
    const float* __restrict__ bfull, int t, float* __restrict__ scores) {
  int wid = (blockIdx.x * 256 + threadIdx.x) >> 6;   // (b,r) pair
  int lane = threadIdx.x & 63;
  if (wid >= 1500) return;
  int b = wid / 15;
  const float* a1 = att1 + (size_t)wid * 512;
  const float* tp = ttop + ((size_t)b * 5 + t) * 512;
  float s = 0.f;
#pragma unroll
  for (int j = 0; j < 8; ++j) {
    int n = lane * 8 + j;
    float ad = bdec[n] + padec[(size_t)b * 512 + n]
             + padec[(size_t)(112 + b) * 512 + n]
             + padec[(size_t)(224 + b) * 512 + n]
             + padec[(size_t)(336 + b) * 512 + n];
    float v = a1[n] + ad + tp[n];
    s += fmaxf(v, 0.f) * wfull[n];
  }
#pragma unroll
  for (int o = 32; o; o >>= 1) s += __shfl_down(s, o, 64);
  if (lane == 0) scores[wid] = s + bfull[0];
}

__global__ __launch_bounds__(256) void k_softawe(const float* __restrict__ scores,
    const float* __restrict__ imgf, unsigned short* __restrict__ X2) {
  int b = blockIdx.x;
  __shared__ float al[16];
  if (threadIdx.x == 0) {
    float m = -1e30f;
    for (int r = 0; r < 15; ++r) m = fmaxf(m, scores[b * 15 + r]);
    float e[15]; float sum = 0.f;
    for (int r = 0; r < 15; ++r) { e[r] = expf(scores[b * 15 + r] - m); sum += e[r]; }
    float inv = 1.f / sum;
    for (int r = 0; r < 15; ++r) al[r] = e[r] * inv;
  }
  __syncthreads();
  for (int f = threadIdx.x; f < 4096; f += 256) {
    float s = 0.f;
#pragma unroll
    for (int r = 0; r < 15; ++r) s += al[r] * imgf[((size_t)b * 15 + r) * 4096 + f];
    X2[(size_t)b * 6144 + f] = f2bf(s);
  }
}

__global__ __launch_bounds__(256) void k_lstm2(const float* __restrict__ P,
    const float* __restrict__ bih, const float* __restrict__ bhh,
    float* __restrict__ c2, unsigned short* __restrict__ Xh2,
    unsigned short* __restrict__ X1, unsigned short* __restrict__ X2) {
  int idx = blockIdx.x * 256 + threadIdx.x;          // 100*1024
  int b = idx >> 10, j = idx & 1023;
  float g[4];
#pragma unroll
  for (int x = 0; x < 4; ++x) {
    int col = (x << 10) + j;
    float s = bih[col] + bhh[col];
#pragma unroll
    for (int sl = 0; sl < 12; ++sl) s += P[((size_t)sl * 112 + b) * 4096 + col];
    g[x] = s;
  }
  float c = sigm(g[1]) * c2[idx] + sigm(g[0]) * tanhf(g[2]);
  float h = sigm(g[3]) * tanhf(c);
  c2[idx] = c;
  unsigned short hb = f2bf(h);
  Xh2[idx] = hb;
  X1[b * 2048 + j] = hb;
  X2[(size_t)b * 6144 + 5120 + j] = hb;
}

__global__ __launch_bounds__(256) void k_eppred(const float* __restrict__ P,
    const float* __restrict__ bias, float* __restrict__ outp, int t) {
  int idx = blockIdx.x * 256 + threadIdx.x;          // 100*10000
  if (idx >= 1000000) return;
  int b = idx / 10000, v = idx - b * 10000;
  outp[((size_t)b * 5 + t) * 10000 + v] =
      P[(size_t)b * 10000 + v] + P[(size_t)(112 + b) * 10000 + v] + bias[v];
}

// ---------------------------------------------------------------------------
extern "C" void kernel_launch(void* const* d_in, const int* in_sizes, int n_in,
                              void* d_out, int out_size, void* d_ws, size_t ws_size,
                              hipStream_t stream) {
  (void)in_sizes; (void)n_in; (void)out_size;
  const float* imgf  = (const float*)d_in[0];
  const int*   caps  = (const int*)d_in[1];
  const int*   lens  = (const int*)d_in[2];
  const float* W_lt  = (const float*)d_in[3];
  const float* b_lt  = (const float*)d_in[4];
  const float* convw = (const float*)d_in[5];
  const float* convb = (const float*)d_in[6];
  const float* W_feat = (const float*)d_in[7];
  const float* b_feat = (const float*)d_in[8];
  const float* W_dec = (const float*)d_in[9];
  const float* b_dec = (const float*)d_in[10];
  const float* W_top = (const float*)d_in[11];
  const float* b_top = (const float*)d_in[12];
  const float* W_full = (const float*)d_in[13];
  const float* b_full = (const float*)d_in[14];
  const float* emb   = (const float*)d_in[15];
  const float* W_ih1 = (const float*)d_in[16];
  const float* W_hh1 = (const float*)d_in[17];
  const float* b_ih1 = (const float*)d_in[18];
  const float* b_hh1 = (const float*)d_in[19];
  const float* W_ih2 = (const float*)d_in[20];
  const float* W_hh2 = (const float*)d_in[21];
  const float* b_ih2 = (const float*)d_in[22];
  const float* b_hh2 = (const float*)d_in[23];
  const float* W_fc1 = (const float*)d_in[24];
  const float* b_fc1 = (const float*)d_in[25];
  const float* W_fc  = (const float*)d_in[26];
  const float* b_fc  = (const float*)d_in[27];
  float* out = (float*)d_out;

  char* ws = (char*)d_ws;
  size_t off = 0;
  auto alloc = [&](size_t bytes) -> size_t {
    size_t o = off; off = (off + bytes + 255) & ~(size_t)255; return o;
  };
  const size_t oXimg  = alloc(1568ull * 4096 * 2);   // bf16 padded image feats
  const size_t oXmean = alloc(112ull * 4096 * 2);
  const size_t oXemb  = alloc(560ull * 1024 * 2);
  const size_t oZERO  = off;                         // ---- zero block start
  const size_t oX1    = alloc(112ull * 2048 * 2);    // [h2 | h1] bf16
  const size_t oX2    = alloc(112ull * 6144 * 2);    // [awe | h1 | h2prev] bf16
  const size_t oXh1   = alloc(112ull * 1024 * 2);
  const size_t oXh2   = alloc(112ull * 1024 * 2);
  const size_t oc1    = alloc(100ull * 1024 * 4);
  const size_t oc2    = alloc(100ull * 1024 * 4);
  const size_t zeroBytes = off - oZERO;              // ---- zero block end
  const size_t olin   = alloc(1568ull * 1024 * 4);
  const size_t otop   = alloc(100ull * 2500 * 4);
  const size_t ottop  = alloc(500ull * 512 * 4);
  const size_t oatt1  = alloc(1568ull * 512 * 4);
  const size_t oscore = alloc(1536ull * 4);
  const size_t ogb1   = alloc(112ull * 4096 * 4);
  const size_t ogemb  = alloc(560ull * 4096 * 4);
  const size_t owords = alloc(512ull * 4);
  const size_t opg    = alloc(12ull * 112 * 4096 * 4); // shared split-K partials
  const size_t opp    = alloc(2ull * 112 * 10000 * 4); // preds partials / adec partials
  if (ws_size < off) return;  // insufficient scratch — clean fail

  unsigned short* Ximg  = (unsigned short*)(ws + oXimg);
  unsigned short* Xmean = (unsigned short*)(ws + oXmean);
  unsigned short* Xemb  = (unsigned short*)(ws + oXemb);
  unsigned short* X1    = (unsigned short*)(ws + oX1);
  unsigned short* X2    = (unsigned short*)(ws + oX2);
  unsigned short* Xh1   = (unsigned short*)(ws + oXh1);
  unsigned short* Xh2   = (unsigned short*)(ws + oXh2);
  float* c1    = (float*)(ws + oc1);
  float* c2    = (float*)(ws + oc2);
  float* lin   = (float*)(ws + olin);
  float* topics = (float*)(ws + otop);
  float* ttop  = (float*)(ws + ottop);
  float* att1  = (float*)(ws + oatt1);
  float* score = (float*)(ws + oscore);
  float* gb1   = (float*)(ws + ogb1);
  float* gemb  = (float*)(ws + ogemb);
  int*   words = (int*)(ws + owords);
  float* pg    = (float*)(ws + opg);
  float* pp    = (float*)(ws + opp);

  const long long S4 = 112ll * 4096;   // gate partial slot stride
  const long long SA = 112ll * 512;    // adec partial slot stride
  const long long SP = 112ll * 10000;  // preds partial slot stride

  hipMemsetAsync(ws + oZERO, 0, zeroBytes, stream);

  // -------- phase A (once) --------
  k_ximg<<<25088, 256, 0, stream>>>(imgf, Ximg);
  k_mean<<<1792, 256, 0, stream>>>(imgf, Xmean);
  gemm_bt<<<dim3(16, 14, 1), 256, 0, stream>>>(Ximg, 4096, W_lt, 4096, 1024,
                                               lin, 4096, b_lt, 0);
  k_conv<<<100, 512, 0, stream>>>(lin, convw, convb, topics);
  k_ttop<<<1000, 256, 0, stream>>>(topics, W_top, b_top, ttop);
  gemm_bt<<<dim3(8, 14, 1), 256, 0, stream>>>(Ximg, 4096, W_feat, 4096, 512,
                                              att1, 4096, b_feat, 0);
  k_words<<<2, 256, 0, stream>>>(caps, lens, words, out + 10026000);
  k_caps<<<102, 256, 0, stream>>>(caps, out + 10000000);
  k_gather<<<2240, 256, 0, stream>>>(emb, words, Xemb);
  // img_mean panel of W_ih1 (cols 1024..5119), applied once
  gemm_bt<<<dim3(64, 1, 8), 256, 0, stream>>>(Xmean, 4096, W_ih1 + 1024, 6144, 4096,
                                              pg, 512, nullptr, S4);
  k_gbase1<<<1792, 256, 0, stream>>>(pg, b_ih1, b_hh1, gb1);
  // emb panel of W_ih1 (cols 5120..6143), all 5 steps at once
  gemm_bt<<<dim3(64, 5, 1), 256, 0, stream>>>(Xemb, 1024, W_ih1 + 5120, 6144, 4096,
                                              gemb, 1024, nullptr, 0);

  // -------- recurrent steps --------
  for (int t = 0; t < 5; ++t) {
    // gates1 partials: h2 panel (slots 0..3) + W_hh1 (slots 4..7)
    gemm_bt<<<dim3(64, 1, 4), 256, 0, stream>>>(X1, 2048, W_ih1, 6144, 4096,
                                                pg, 256, nullptr, S4);
    gemm_bt<<<dim3(64, 1, 4), 256, 0, stream>>>(X1 + 1024, 2048, W_hh1, 1024, 4096,
                                                pg + 4 * S4, 256, nullptr, S4);
    k_lstm1<<<400, 256, 0, stream>>>(pg, gb1, gemb, t, c1, Xh1, X1, X2);
    // adec partials into pp slots 0..3
    gemm_bt<<<dim3(8, 1, 4), 256, 0, stream>>>(Xh1, 1024, W_dec, 1024, 512,
                                               pp, 256, nullptr, SA);
    k_att<<<375, 256, 0, stream>>>(att1, pp, b_dec, ttop, W_full, b_full, t, score);
    k_softawe<<<100, 256, 0, stream>>>(score, imgf, X2);
    // preds1
    gemm_bt<<<dim3(157, 1, 2), 256, 0, stream>>>(Xh1, 1024, W_fc1, 1024, 10000,
                                                 pp, 512, nullptr, SP);
    k_eppred<<<3907, 256, 0, stream>>>(pp, b_fc1, out + 5000000, t);
    // gates2 partials: [awe|h1] panel (slots 0..7) + W_hh2 (slots 8..11)
    gemm_bt<<<dim3(64, 1, 8), 256, 0, stream>>>(X2, 6144, W_ih2, 5120, 4096,
                                                pg, 640, nullptr, S4);
    gemm_bt<<<dim3(64, 1, 4), 256, 0, stream>>>(X2 + 5120, 6144, W_hh2, 1024, 4096,
                                                pg + 8 * S4, 256, nullptr, S4);
    k_lstm2<<<400, 256, 0, stream>>>(pg, b_ih2, b_hh2, c2, Xh2, X1, X2);
    // preds
    gemm_bt<<<dim3(157, 1, 2), 256, 0, stream>>>(Xh2, 1024, W_fc, 1024, 10000,
                                                 pp, 512, nullptr, SP);
    k_eppred<<<3907, 256, 0, stream>>>(pp, b_fc, out, t);
  }
}

// Round 2
// 1306.615 us; speedup vs baseline: 1.6232x; 1.6232x over previous
//
#include <hip/hip_runtime.h>

typedef __attribute__((ext_vector_type(8))) short short8;
typedef __attribute__((ext_vector_type(4))) short short4v;
typedef __attribute__((ext_vector_type(4))) float f32x4;

__device__ __forceinline__ unsigned short f2bf(float f) {
  unsigned int u = __float_as_uint(f);
  u += 0x7fffu + ((u >> 16) & 1u);   // RNE round to bf16
  return (unsigned short)(u >> 16);
}
__device__ __forceinline__ float bf2f(unsigned short u) {
  return __uint_as_float(((unsigned int)u) << 16);
}
__device__ __forceinline__ float sigm(float x) { return 1.f / (1.f + expf(-x)); }

// ---------------------------------------------------------------------------
// Skinny GEMM, f32 weights (phase-A only):
//   C[z*slotStride + (mbase+m)*N + n] = sum_{k in chunk z} X_bf16[m][k]*W_f32[n][k]
// ---------------------------------------------------------------------------
template<int KITERS>
__global__ __launch_bounds__(256) void gemm_bt(
    const unsigned short* __restrict__ X, int ldx,
    const float* __restrict__ W, int ldw, int N,
    float* __restrict__ C, long long slotStride)
{
  const int lane = threadIdx.x & 63;
  const int wv   = threadIdx.x >> 6;
  const int mbase = blockIdx.y * 112;
  const int l16 = lane & 15;
  const int kg  = (lane >> 4) * 8;
  const int ncol = blockIdx.x * 64 + wv * 16 + l16;
  const int nrow = (ncol < N) ? ncol : (N - 1);
  const int k0 = blockIdx.z * (KITERS * 32);
  C += (long long)blockIdx.z * slotStride;

  const float* wp = W + (size_t)nrow * ldw + kg + k0;
  const unsigned short* xp = X + (size_t)(mbase + l16) * ldx + kg + k0;

  f32x4 acc[7];
#pragma unroll
  for (int i = 0; i < 7; ++i) acc[i] = (f32x4){0.f, 0.f, 0.f, 0.f};

#pragma unroll 4
  for (int it = 0; it < KITERS; ++it) {
    const int k = it * 32;
    const float4 w0 = *(const float4*)(wp + k);
    const float4 w1 = *(const float4*)(wp + k + 4);
    short8 bfr;
    bfr[0] = (short)f2bf(w0.x); bfr[1] = (short)f2bf(w0.y);
    bfr[2] = (short)f2bf(w0.z); bfr[3] = (short)f2bf(w0.w);
    bfr[4] = (short)f2bf(w1.x); bfr[5] = (short)f2bf(w1.y);
    bfr[6] = (short)f2bf(w1.z); bfr[7] = (short)f2bf(w1.w);
#pragma unroll
    for (int mt = 0; mt < 7; ++mt) {
      short8 a = *(const short8*)(xp + (size_t)mt * 16 * ldx + k);
      acc[mt] = __builtin_amdgcn_mfma_f32_16x16x32_bf16(a, bfr, acc[mt], 0, 0, 0);
    }
  }
  if (ncol < N) {
    const int r0 = (lane >> 4) * 4;
#pragma unroll
    for (int mt = 0; mt < 7; ++mt)
#pragma unroll
      for (int r = 0; r < 4; ++r)
        C[(size_t)(mbase + mt * 16 + r0 + r) * N + ncol] = acc[mt][r];
  }
}

// ---------------------------------------------------------------------------
// Skinny GEMM, bf16 weights (the per-step workhorse)
// ---------------------------------------------------------------------------
template<int KITERS>
__global__ __launch_bounds__(256) void gemm_bb(
    const unsigned short* __restrict__ X, int ldx,
    const unsigned short* __restrict__ W, int ldw, int N,
    float* __restrict__ C, long long slotStride)
{
  const int lane = threadIdx.x & 63;
  const int wv   = threadIdx.x >> 6;
  const int mbase = blockIdx.y * 112;
  const int l16 = lane & 15;
  const int kg  = (lane >> 4) * 8;
  const int ncol = blockIdx.x * 64 + wv * 16 + l16;
  const int nrow = (ncol < N) ? ncol : (N - 1);
  const int k0 = blockIdx.z * (KITERS * 32);
  C += (long long)blockIdx.z * slotStride;

  const unsigned short* wp = W + (size_t)nrow * ldw + kg + k0;
  const unsigned short* xp = X + (size_t)(mbase + l16) * ldx + kg + k0;

  f32x4 acc[7];
#pragma unroll
  for (int i = 0; i < 7; ++i) acc[i] = (f32x4){0.f, 0.f, 0.f, 0.f};

#pragma unroll 4
  for (int it = 0; it < KITERS; ++it) {
    const int k = it * 32;
    short8 bfr = *(const short8*)(wp + k);
#pragma unroll
    for (int mt = 0; mt < 7; ++mt) {
      short8 a = *(const short8*)(xp + (size_t)mt * 16 * ldx + k);
      acc[mt] = __builtin_amdgcn_mfma_f32_16x16x32_bf16(a, bfr, acc[mt], 0, 0, 0);
    }
  }
  if (ncol < N) {
    const int r0 = (lane >> 4) * 4;
#pragma unroll
    for (int mt = 0; mt < 7; ++mt)
#pragma unroll
      for (int r = 0; r < 4; ++r)
        C[(size_t)(mbase + mt * 16 + r0 + r) * N + ncol] = acc[mt][r];
  }
}

// --------------------------- weight pack/convert ---------------------------
__global__ __launch_bounds__(256) void k_cvt4(const float* __restrict__ src,
                                              unsigned short* __restrict__ dst, int n4) {
  int i = blockIdx.x * 256 + threadIdx.x;
  if (i >= n4) return;
  float4 v = ((const float4*)src)[i];
  short4v o; o[0] = (short)f2bf(v.x); o[1] = (short)f2bf(v.y);
  o[2] = (short)f2bf(v.z); o[3] = (short)f2bf(v.w);
  ((short4v*)dst)[i] = o;
}

__global__ __launch_bounds__(256) void k_pack_g1(const float* __restrict__ Wih1,
    const float* __restrict__ Whh1, unsigned short* __restrict__ Wg1) {
  int i = blockIdx.x * 256 + threadIdx.x;            // 4096*512 vec4
  if (i >= 4096 * 512) return;
  int row = i >> 9, c4 = i & 511;
  const float* src = (c4 < 256) ? Wih1 + (size_t)row * 6144 + c4 * 4
                                : Whh1 + (size_t)row * 1024 + (c4 - 256) * 4;
  float4 v = *(const float4*)src;
  short4v o; o[0] = (short)f2bf(v.x); o[1] = (short)f2bf(v.y);
  o[2] = (short)f2bf(v.z); o[3] = (short)f2bf(v.w);
  ((short4v*)Wg1)[i] = o;
}

__global__ __launch_bounds__(256) void k_pack_g2(const float* __restrict__ Wih2,
    const float* __restrict__ Whh2, unsigned short* __restrict__ Wg2) {
  int i = blockIdx.x * 256 + threadIdx.x;            // 4096*1536 vec4
  if (i >= 4096 * 1536) return;
  int row = i / 1536, c4 = i - row * 1536;
  const float* src = (c4 < 1280) ? Wih2 + (size_t)row * 5120 + c4 * 4
                                 : Whh2 + (size_t)row * 1024 + (c4 - 1280) * 4;
  float4 v = *(const float4*)src;
  short4v o; o[0] = (short)f2bf(v.x); o[1] = (short)f2bf(v.y);
  o[2] = (short)f2bf(v.z); o[3] = (short)f2bf(v.w);
  ((short4v*)Wg2)[i] = o;
}

// --------------------------- phase-A helper kernels ------------------------
__global__ __launch_bounds__(256) void k_ximg(const float* __restrict__ src,
                                              unsigned short* __restrict__ dst) {
  int idx = blockIdx.x * 256 + threadIdx.x;          // 1568*4096
  int row = idx >> 12;
  dst[idx] = (row < 1500) ? f2bf(src[idx]) : (unsigned short)0;
}

__global__ __launch_bounds__(256) void k_mean(const float* __restrict__ img,
                                              unsigned short* __restrict__ dst) {
  int idx = blockIdx.x * 256 + threadIdx.x;          // 112*4096
  int b = idx >> 12, f = idx & 4095;
  unsigned short r = 0;
  if (b < 100) {
    float s = 0.f;
    for (int rr = 0; rr < 15; ++rr) s += img[((size_t)b * 15 + rr) * 4096 + f];
    r = f2bf(s * (1.f / 15.f));
  }
  dst[idx] = r;
}

__global__ __launch_bounds__(256) void k_reduce(const float* __restrict__ P,
    long long ss, int nslots, const float* __restrict__ bias, int colmask,
    float* __restrict__ out, int total) {
  int idx = blockIdx.x * 256 + threadIdx.x;
  if (idx >= total) return;
  float s = bias ? bias[idx & colmask] : 0.f;
  for (int sl = 0; sl < nslots; ++sl) s += P[(size_t)sl * ss + idx];
  out[idx] = s;
}

__global__ __launch_bounds__(512) void k_conv(const float* __restrict__ lin,
    const float* __restrict__ cw, const float* __restrict__ cb,
    float* __restrict__ topics) {
  int b = blockIdx.x;
  __shared__ float L[15 * 1024];
  for (int i = threadIdx.x; i < 15 * 1024; i += 512) L[i] = lin[(size_t)b * 15360 + i];
  __syncthreads();
  for (int idx = threadIdx.x; idx < 2500; idx += 512) {
    int tt = idx / 500, w = idx - tt * 500;
    float s = cb[tt];
    for (int kh = 0; kh < 15; ++kh) {
      const float* lr = &L[kh * 1024 + 2 * w];
      const float* wr = &cw[(tt * 15 + kh) * 26];
#pragma unroll
      for (int kw = 0; kw < 26; ++kw) s += lr[kw] * wr[kw];
    }
    topics[(size_t)b * 2500 + idx] = s;
  }
}

__global__ __launch_bounds__(256) void k_ttop(const float* __restrict__ topics,
    const float* __restrict__ Wt, const float* __restrict__ btp,
    float* __restrict__ ttop) {
  int idx = blockIdx.x * 256 + threadIdx.x;          // 500*512
  int r = idx >> 9, n = idx & 511;
  const float4* tr = (const float4*)(topics + (size_t)r * 500);
  const float4* wr = (const float4*)(Wt + (size_t)n * 500);
  float s = btp[n];
  for (int k = 0; k < 125; ++k) {
    float4 a = tr[k], w = wr[k];
    s += a.x * w.x + a.y * w.y + a.z * w.z + a.w * w.w;
  }
  ttop[idx] = s;
}

__global__ void k_words(const int* __restrict__ caps, const int* __restrict__ lens,
                        int* __restrict__ words, float* __restrict__ out3) {
  int idx = blockIdx.x * 256 + threadIdx.x;
  if (idx >= 500) return;
  int len = lens[idx];
  words[idx] = caps[idx * 52 + len - 1];
  out3[idx] = (float)(len - 1);
}

__global__ void k_caps(const int* __restrict__ caps, float* __restrict__ out2) {
  int idx = blockIdx.x * 256 + threadIdx.x;
  if (idx < 26000) out2[idx] = (float)caps[idx];
}

__global__ __launch_bounds__(256) void k_gather(const float* __restrict__ emb,
    const int* __restrict__ words, unsigned short* __restrict__ Xemb) {
  int idx = blockIdx.x * 256 + threadIdx.x;          // 560*1024
  int bt = idx >> 10, e = idx & 1023;
  Xemb[idx] = (bt < 500) ? f2bf(emb[(size_t)words[bt] * 1024 + e]) : (unsigned short)0;
}

__global__ __launch_bounds__(256) void k_gbase1(const float* __restrict__ P,
    const float* __restrict__ bih, const float* __restrict__ bhh,
    float* __restrict__ gb) {
  int idx = blockIdx.x * 256 + threadIdx.x;          // 112*4096
  int m = idx >> 12, n = idx & 4095;
  float s = bih[n] + bhh[n];
#pragma unroll
  for (int sl = 0; sl < 8; ++sl) s += P[((size_t)sl * 112 + m) * 4096 + n];
  gb[idx] = s;
}

// ------------------------------ per-step kernels ---------------------------
__global__ __launch_bounds__(256) void k_lstm1(const float* __restrict__ P,
    const float* __restrict__ gb1, const float* __restrict__ gemb, int t,
    float* __restrict__ c1, unsigned short* __restrict__ Xh1,
    unsigned short* __restrict__ X1, unsigned short* __restrict__ X2) {
  int idx = blockIdx.x * 256 + threadIdx.x;          // 100*1024
  int b = idx >> 10, j = idx & 1023;
  float g[4];
#pragma unroll
  for (int x = 0; x < 4; ++x) {
    int col = (x << 10) + j;
    float s = gb1[b * 4096 + col] + gemb[((size_t)b * 5 + t) * 4096 + col];
#pragma unroll
    for (int sl = 0; sl < 8; ++sl) s += P[((size_t)sl * 112 + b) * 4096 + col];
    g[x] = s;
  }
  float c = sigm(g[1]) * c1[idx] + sigm(g[0]) * tanhf(g[2]);
  float h = sigm(g[3]) * tanhf(c);
  c1[idx] = c;
  unsigned short hb = f2bf(h);
  Xh1[idx] = hb;
  X1[b * 2048 + 1024 + j] = hb;
  X2[(size_t)b * 6144 + 4096 + j] = hb;
}

__global__ __launch_bounds__(256) void k_att(const float* __restrict__ att1,
    const float* __restrict__ padec, const float* __restrict__ bdec,
    const float* __restrict__ ttop, const float* __restrict__ wfull,
    const float* __restrict__ bfull, int t, float* __restrict__ scores) {
  int wid = (blockIdx.x * 256 + threadIdx.x) >> 6;   // (b,r) pair
  int lane = threadIdx.x & 63;
  if (wid >= 1500) return;
  int b = wid / 15;
  const float* a1 = att1 + (size_t)wid * 512;
  const float* tp = ttop + ((size_t)b * 5 + t) * 512;
  float s = 0.f;
#pragma unroll
  for (int j = 0; j < 8; ++j) {
    int n = lane * 8 + j;
    float ad = bdec[n] + padec[(size_t)b * 512 + n]
             + padec[(size_t)(112 + b) * 512 + n]
             + padec[(size_t)(224 + b) * 512 + n]
             + padec[(size_t)(336 + b) * 512 + n];
    float v = a1[n] + ad + tp[n];
    s += fmaxf(v, 0.f) * wfull[n];
  }
#pragma unroll
  for (int o = 32; o; o >>= 1) s += __shfl_down(s, o, 64);
  if (lane == 0) scores[wid] = s + bfull[0];
}

__global__ __launch_bounds__(256) void k_softawe(const float* __restrict__ scores,
    const unsigned short* __restrict__ Ximg, unsigned short* __restrict__ X2) {
  int b = blockIdx.x;
  __shared__ float al[16];
  if (threadIdx.x == 0) {
    float m = -1e30f;
    for (int r = 0; r < 15; ++r) m = fmaxf(m, scores[b * 15 + r]);
    float e[15]; float sum = 0.f;
    for (int r = 0; r < 15; ++r) { e[r] = expf(scores[b * 15 + r] - m); sum += e[r]; }
    float inv = 1.f / sum;
    for (int r = 0; r < 15; ++r) al[r] = e[r] * inv;
  }
  __syncthreads();
  for (int f = threadIdx.x; f < 4096; f += 256) {
    float s = 0.f;
#pragma unroll
    for (int r = 0; r < 15; ++r) s += al[r] * bf2f(Ximg[((size_t)b * 15 + r) * 4096 + f]);
    X2[(size_t)b * 6144 + f] = f2bf(s);
  }
}

__global__ __launch_bounds__(256) void k_lstm2(const float* __restrict__ P,
    const float* __restrict__ bih, const float* __restrict__ bhh,
    float* __restrict__ c2, unsigned short* __restrict__ Xh2,
    unsigned short* __restrict__ X1, unsigned short* __restrict__ X2) {
  int idx = blockIdx.x * 256 + threadIdx.x;          // 100*1024
  int b = idx >> 10, j = idx & 1023;
  float g[4];
#pragma unroll
  for (int x = 0; x < 4; ++x) {
    int col = (x << 10) + j;
    float s = bih[col] + bhh[col];
#pragma unroll
    for (int sl = 0; sl < 12; ++sl) s += P[((size_t)sl * 112 + b) * 4096 + col];
    g[x] = s;
  }
  float c = sigm(g[1]) * c2[idx] + sigm(g[0]) * tanhf(g[2]);
  float h = sigm(g[3]) * tanhf(c);
  c2[idx] = c;
  unsigned short hb = f2bf(h);
  Xh2[idx] = hb;
  X1[b * 2048 + j] = hb;
  X2[(size_t)b * 6144 + 5120 + j] = hb;
}

__global__ __launch_bounds__(256) void k_eppred(const float* __restrict__ P,
    const float* __restrict__ bias, float* __restrict__ outp, int t) {
  int idx = blockIdx.x * 256 + threadIdx.x;          // 100*10000
  if (idx >= 1000000) return;
  int b = idx / 10000, v = idx - b * 10000;
  outp[((size_t)b * 5 + t) * 10000 + v] = bias[v]
      + P[(size_t)b * 10000 + v]       + P[(size_t)(112 + b) * 10000 + v]
      + P[(size_t)(224 + b) * 10000 + v] + P[(size_t)(336 + b) * 10000 + v];
}

// ---------------------------------------------------------------------------
extern "C" void kernel_launch(void* const* d_in, const int* in_sizes, int n_in,
                              void* d_out, int out_size, void* d_ws, size_t ws_size,
                              hipStream_t stream) {
  (void)in_sizes; (void)n_in; (void)out_size;
  const float* imgf  = (const float*)d_in[0];
  const int*   caps  = (const int*)d_in[1];
  const int*   lens  = (const int*)d_in[2];
  const float* W_lt  = (const float*)d_in[3];
  const float* b_lt  = (const float*)d_in[4];
  const float* convw = (const float*)d_in[5];
  const float* convb = (const float*)d_in[6];
  const float* W_feat = (const float*)d_in[7];
  const float* b_feat = (const float*)d_in[8];
  const float* W_dec = (const float*)d_in[9];
  const float* b_dec = (const float*)d_in[10];
  const float* W_top = (const float*)d_in[11];
  const float* b_top = (const float*)d_in[12];
  const float* W_full = (const float*)d_in[13];
  const float* b_full = (const float*)d_in[14];
  const float* emb   = (const float*)d_in[15];
  const float* W_ih1 = (const float*)d_in[16];
  const float* W_hh1 = (const float*)d_in[17];
  const float* b_ih1 = (const float*)d_in[18];
  const float* b_hh1 = (const float*)d_in[19];
  const float* W_ih2 = (const float*)d_in[20];
  const float* W_hh2 = (const float*)d_in[21];
  const float* b_ih2 = (const float*)d_in[22];
  const float* b_hh2 = (const float*)d_in[23];
  const float* W_fc1 = (const float*)d_in[24];
  const float* b_fc1 = (const float*)d_in[25];
  const float* W_fc  = (const float*)d_in[26];
  const float* b_fc  = (const float*)d_in[27];
  float* out = (float*)d_out;

  char* ws = (char*)d_ws;
  size_t off = 0;
  auto alloc = [&](size_t bytes) -> size_t {
    size_t o = off; off = (off + bytes + 255) & ~(size_t)255; return o;
  };
  const size_t oXimg  = alloc(1568ull * 4096 * 2);
  const size_t oXmean = alloc(112ull * 4096 * 2);
  const size_t oXemb  = alloc(560ull * 1024 * 2);
  const size_t oZERO  = off;                         // ---- zero block start
  const size_t oX1    = alloc(112ull * 2048 * 2);    // [h2 | h1] bf16
  const size_t oX2    = alloc(112ull * 6144 * 2);    // [awe | h1 | h2prev] bf16
  const size_t oXh1   = alloc(112ull * 1024 * 2);
  const size_t oXh2   = alloc(112ull * 1024 * 2);
  const size_t oc1    = alloc(100ull * 1024 * 4);
  const size_t oc2    = alloc(100ull * 1024 * 4);
  const size_t zeroBytes = off - oZERO;              // ---- zero block end
  const size_t olin   = alloc(1568ull * 1024 * 4);
  const size_t otop   = alloc(100ull * 2500 * 4);
  const size_t ottop  = alloc(500ull * 512 * 4);
  const size_t oatt1  = alloc(1568ull * 512 * 4);
  const size_t oscore = alloc(1536ull * 4);
  const size_t ogb1   = alloc(112ull * 4096 * 4);
  const size_t ogemb  = alloc(560ull * 4096 * 4);
  const size_t owords = alloc(512ull * 4);
  const size_t opg    = alloc(12ull * 112 * 4096 * 4);  // gate split-K partials
  const size_t opp    = alloc(4ull * 112 * 10000 * 4);  // preds/adec partials
  const size_t opl    = alloc(8ull * 1568 * 512 * 4);   // phase-A partials (reused)
  const size_t oWg1   = alloc(4096ull * 2048 * 2);      // [Wih1.h2 | Whh1] bf16
  const size_t oWg2   = alloc(4096ull * 6144 * 2);      // [Wih2 | Whh2] bf16
  const size_t oWfc1b = alloc(10000ull * 1024 * 2);
  const size_t oWfcb  = alloc(10000ull * 1024 * 2);
  const size_t oWdecb = alloc(512ull * 1024 * 2);
  if (ws_size < off) return;  // insufficient scratch — loud fail

  unsigned short* Ximg  = (unsigned short*)(ws + oXimg);
  unsigned short* Xmean = (unsigned short*)(ws + oXmean);
  unsigned short* Xemb  = (unsigned short*)(ws + oXemb);
  unsigned short* X1    = (unsigned short*)(ws + oX1);
  unsigned short* X2    = (unsigned short*)(ws + oX2);
  unsigned short* Xh1   = (unsigned short*)(ws + oXh1);
  unsigned short* Xh2   = (unsigned short*)(ws + oXh2);
  float* c1    = (float*)(ws + oc1);
  float* c2    = (float*)(ws + oc2);
  float* lin   = (float*)(ws + olin);
  float* topics = (float*)(ws + otop);
  float* ttop  = (float*)(ws + ottop);
  float* att1  = (float*)(ws + oatt1);
  float* score = (float*)(ws + oscore);
  float* gb1   = (float*)(ws + ogb1);
  float* gemb  = (float*)(ws + ogemb);
  int*   words = (int*)(ws + owords);
  float* pg    = (float*)(ws + opg);
  float* pp    = (float*)(ws + opp);
  float* pl    = (float*)(ws + opl);
  unsigned short* Wg1   = (unsigned short*)(ws + oWg1);
  unsigned short* Wg2   = (unsigned short*)(ws + oWg2);
  unsigned short* Wfc1b = (unsigned short*)(ws + oWfc1b);
  unsigned short* Wfcb  = (unsigned short*)(ws + oWfcb);
  unsigned short* Wdecb = (unsigned short*)(ws + oWdecb);

  const long long S4 = 112ll * 4096;   // gate partial slot stride
  const long long SA = 112ll * 512;    // adec partial slot stride
  const long long SP = 112ll * 10000;  // preds partial slot stride

  hipMemsetAsync(ws + oZERO, 0, zeroBytes, stream);

  // -------- phase A (once) --------
  k_ximg<<<25088, 256, 0, stream>>>(imgf, Ximg);
  k_mean<<<1792, 256, 0, stream>>>(imgf, Xmean);
  // bf16 weight packs (5x-reused weights; ~108 MB bf16 -> L3-resident)
  k_pack_g1<<<8192, 256, 0, stream>>>(W_ih1, W_hh1, Wg1);
  k_pack_g2<<<24576, 256, 0, stream>>>(W_ih2, W_hh2, Wg2);
  k_cvt4<<<10000, 256, 0, stream>>>(W_fc1, Wfc1b, 2560000);
  k_cvt4<<<10000, 256, 0, stream>>>(W_fc, Wfcb, 2560000);
  k_cvt4<<<512, 256, 0, stream>>>(W_dec, Wdecb, 131072);
  // autoencoder linear: split-K z=4 (Kchunk 1024)
  gemm_bt<32><<<dim3(16, 14, 4), 256, 0, stream>>>(Ximg, 4096, W_lt, 4096, 1024,
                                                   pl, 1568ll * 1024);
  k_reduce<<<6272, 256, 0, stream>>>(pl, 1568ll * 1024, 4, b_lt, 1023, lin, 1568 * 1024);
  k_conv<<<100, 512, 0, stream>>>(lin, convw, convb, topics);
  k_ttop<<<1000, 256, 0, stream>>>(topics, W_top, b_top, ttop);
  // att1 = img @ W_feat^T: split-K z=8 (Kchunk 512)
  gemm_bt<16><<<dim3(8, 14, 8), 256, 0, stream>>>(Ximg, 4096, W_feat, 4096, 512,
                                                  pl, 1568ll * 512);
  k_reduce<<<3136, 256, 0, stream>>>(pl, 1568ll * 512, 8, b_feat, 511, att1, 1568 * 512);
  k_words<<<2, 256, 0, stream>>>(caps, lens, words, out + 10026000);
  k_caps<<<102, 256, 0, stream>>>(caps, out + 10000000);
  k_gather<<<2240, 256, 0, stream>>>(emb, words, Xemb);
  // img_mean panel of W_ih1 (cols 1024..5119), once
  gemm_bt<16><<<dim3(64, 1, 8), 256, 0, stream>>>(Xmean, 4096, W_ih1 + 1024, 6144, 4096,
                                                  pg, S4);
  k_gbase1<<<1792, 256, 0, stream>>>(pg, b_ih1, b_hh1, gb1);
  // emb panel of W_ih1 (cols 5120..6143), all 5 steps, split-K z=2
  gemm_bt<16><<<dim3(64, 5, 2), 256, 0, stream>>>(Xemb, 1024, W_ih1 + 5120, 6144, 4096,
                                                  pl, 560ll * 4096);
  k_reduce<<<8960, 256, 0, stream>>>(pl, 560ll * 4096, 2, nullptr, 4095, gemb, 560 * 4096);

  // -------- recurrent steps --------
  for (int t = 0; t < 5; ++t) {
    // gates1 = Wg1 @ [h2|h1prev]: K=2048, z=8 (Kchunk 256)
    gemm_bb<8><<<dim3(64, 1, 8), 256, 0, stream>>>(X1, 2048, Wg1, 2048, 4096, pg, S4);
    k_lstm1<<<400, 256, 0, stream>>>(pg, gb1, gemb, t, c1, Xh1, X1, X2);
    // adec: K=1024, z=4
    gemm_bb<8><<<dim3(8, 1, 4), 256, 0, stream>>>(Xh1, 1024, Wdecb, 1024, 512, pp, SA);
    k_att<<<375, 256, 0, stream>>>(att1, pp, b_dec, ttop, W_full, b_full, t, score);
    k_softawe<<<100, 256, 0, stream>>>(score, Ximg, X2);
    // preds1: K=1024, z=4
    gemm_bb<8><<<dim3(157, 1, 4), 256, 0, stream>>>(Xh1, 1024, Wfc1b, 1024, 10000, pp, SP);
    k_eppred<<<3907, 256, 0, stream>>>(pp, b_fc1, out + 5000000, t);
    // gates2 = Wg2 @ [awe|h1|h2prev]: K=6144, z=12 (Kchunk 512)
    gemm_bb<16><<<dim3(64, 1, 12), 256, 0, stream>>>(X2, 6144, Wg2, 6144, 4096, pg, S4);
    k_lstm2<<<400, 256, 0, stream>>>(pg, b_ih2, b_hh2, c2, Xh2, X1, X2);
    // preds: K=1024, z=4
    gemm_bb<8><<<dim3(157, 1, 4), 256, 0, stream>>>(Xh2, 1024, Wfcb, 1024, 10000, pp, SP);
    k_eppred<<<3907, 256, 0, stream>>>(pp, b_fc, out, t);
  }
}

// Round 3
// 1290.010 us; speedup vs baseline: 1.6441x; 1.0129x over previous
//
#include <hip/hip_runtime.h>

typedef __attribute__((ext_vector_type(8))) short short8;
typedef __attribute__((ext_vector_type(4))) short short4v;
typedef __attribute__((ext_vector_type(4))) float f32x4;

__device__ __forceinline__ unsigned short f2bf(float f) {
  unsigned int u = __float_as_uint(f);
  u += 0x7fffu + ((u >> 16) & 1u);   // RNE round to bf16
  return (unsigned short)(u >> 16);
}
__device__ __forceinline__ float bf2f(unsigned short u) {
  return __uint_as_float(((unsigned int)u) << 16);
}
__device__ __forceinline__ float sigm(float x) { return 1.f / (1.f + expf(-x)); }

// ---------------------------------------------------------------------------
// Skinny GEMM, bf16 weights, 2-stage register prefetch.
//   C[z*slotStride + (mbase+m)*N + n] = sum_{k chunk z} X_bf16[m][k]*W_bf16[n][k]
// ---------------------------------------------------------------------------
template<int KITERS>
__global__ __launch_bounds__(256, 4) void gemm_bb(
    const unsigned short* __restrict__ X, int ldx,
    const unsigned short* __restrict__ W, int ldw, int N,
    float* __restrict__ C, long long slotStride)
{
  const int lane = threadIdx.x & 63;
  const int wv   = threadIdx.x >> 6;
  const int mbase = blockIdx.y * 112;
  const int l16 = lane & 15;
  const int kg  = (lane >> 4) * 8;
  const int ncol = blockIdx.x * 64 + wv * 16 + l16;
  const int nrow = (ncol < N) ? ncol : (N - 1);
  const int k0 = blockIdx.z * (KITERS * 32);
  C += (long long)blockIdx.z * slotStride;

  const unsigned short* wp = W + (size_t)nrow * ldw + kg + k0;
  const unsigned short* xp = X + (size_t)(mbase + l16) * ldx + kg + k0;
  const size_t xstep = (size_t)16 * ldx;

  f32x4 acc[7];
#pragma unroll
  for (int i = 0; i < 7; ++i) acc[i] = (f32x4){0.f, 0.f, 0.f, 0.f};

  short8 wc = *(const short8*)wp;
  short8 xc[7];
#pragma unroll
  for (int mt = 0; mt < 7; ++mt) xc[mt] = *(const short8*)(xp + mt * xstep);

#pragma unroll
  for (int it = 0; it < KITERS; ++it) {
    short8 wn = {};
    short8 xn[7] = {};
    if (it + 1 < KITERS) {                 // compile-time after unroll
      const int k = (it + 1) * 32;
      wn = *(const short8*)(wp + k);
#pragma unroll
      for (int mt = 0; mt < 7; ++mt)
        xn[mt] = *(const short8*)(xp + mt * xstep + k);
    }
#pragma unroll
    for (int mt = 0; mt < 7; ++mt)
      acc[mt] = __builtin_amdgcn_mfma_f32_16x16x32_bf16(xc[mt], wc, acc[mt], 0, 0, 0);
    wc = wn;
#pragma unroll
    for (int mt = 0; mt < 7; ++mt) xc[mt] = xn[mt];
  }
  if (ncol < N) {
    const int r0 = (lane >> 4) * 4;
#pragma unroll
    for (int mt = 0; mt < 7; ++mt)
#pragma unroll
      for (int r = 0; r < 4; ++r)
        C[(size_t)(mbase + mt * 16 + r0 + r) * N + ncol] = acc[mt][r];
  }
}

// ---------------------------------------------------------------------------
// Same, f32 weights (one-time-use weight panels only), prefetched.
// ---------------------------------------------------------------------------
template<int KITERS>
__global__ __launch_bounds__(256, 4) void gemm_bt(
    const unsigned short* __restrict__ X, int ldx,
    const float* __restrict__ W, int ldw, int N,
    float* __restrict__ C, long long slotStride)
{
  const int lane = threadIdx.x & 63;
  const int wv   = threadIdx.x >> 6;
  const int mbase = blockIdx.y * 112;
  const int l16 = lane & 15;
  const int kg  = (lane >> 4) * 8;
  const int ncol = blockIdx.x * 64 + wv * 16 + l16;
  const int nrow = (ncol < N) ? ncol : (N - 1);
  const int k0 = blockIdx.z * (KITERS * 32);
  C += (long long)blockIdx.z * slotStride;

  const float* wp = W + (size_t)nrow * ldw + kg + k0;
  const unsigned short* xp = X + (size_t)(mbase + l16) * ldx + kg + k0;
  const size_t xstep = (size_t)16 * ldx;

  f32x4 acc[7];
#pragma unroll
  for (int i = 0; i < 7; ++i) acc[i] = (f32x4){0.f, 0.f, 0.f, 0.f};

  auto cvt = [](float4 a, float4 b) {
    short8 o;
    o[0] = (short)f2bf(a.x); o[1] = (short)f2bf(a.y);
    o[2] = (short)f2bf(a.z); o[3] = (short)f2bf(a.w);
    o[4] = (short)f2bf(b.x); o[5] = (short)f2bf(b.y);
    o[6] = (short)f2bf(b.z); o[7] = (short)f2bf(b.w);
    return o;
  };

  float4 w0 = *(const float4*)wp, w1 = *(const float4*)(wp + 4);
  short8 xc[7];
#pragma unroll
  for (int mt = 0; mt < 7; ++mt) xc[mt] = *(const short8*)(xp + mt * xstep);

#pragma unroll
  for (int it = 0; it < KITERS; ++it) {
    float4 v0 = {}, v1 = {};
    short8 xn[7] = {};
    if (it + 1 < KITERS) {
      const int k = (it + 1) * 32;
      v0 = *(const float4*)(wp + k);
      v1 = *(const float4*)(wp + k + 4);
#pragma unroll
      for (int mt = 0; mt < 7; ++mt)
        xn[mt] = *(const short8*)(xp + mt * xstep + k);
    }
    short8 wc = cvt(w0, w1);
#pragma unroll
    for (int mt = 0; mt < 7; ++mt)
      acc[mt] = __builtin_amdgcn_mfma_f32_16x16x32_bf16(xc[mt], wc, acc[mt], 0, 0, 0);
    w0 = v0; w1 = v1;
#pragma unroll
    for (int mt = 0; mt < 7; ++mt) xc[mt] = xn[mt];
  }
  if (ncol < N) {
    const int r0 = (lane >> 4) * 4;
#pragma unroll
    for (int mt = 0; mt < 7; ++mt)
#pragma unroll
      for (int r = 0; r < 4; ++r)
        C[(size_t)(mbase + mt * 16 + r0 + r) * N + ncol] = acc[mt][r];
  }
}

// --------------------------- weight pack/convert ---------------------------
__global__ __launch_bounds__(256) void k_cvt4(const float* __restrict__ src,
                                              unsigned short* __restrict__ dst, int n4) {
  int i = blockIdx.x * 256 + threadIdx.x;
  if (i >= n4) return;
  float4 v = ((const float4*)src)[i];
  short4v o; o[0] = (short)f2bf(v.x); o[1] = (short)f2bf(v.y);
  o[2] = (short)f2bf(v.z); o[3] = (short)f2bf(v.w);
  ((short4v*)dst)[i] = o;
}

__global__ __launch_bounds__(256) void k_pack_g1(const float* __restrict__ Wih1,
    const float* __restrict__ Whh1, unsigned short* __restrict__ Wg1) {
  int i = blockIdx.x * 256 + threadIdx.x;            // 4096*512 vec4
  if (i >= 4096 * 512) return;
  int row = i >> 9, c4 = i & 511;
  const float* src = (c4 < 256) ? Wih1 + (size_t)row * 6144 + c4 * 4
                                : Whh1 + (size_t)row * 1024 + (c4 - 256) * 4;
  float4 v = *(const float4*)src;
  short4v o; o[0] = (short)f2bf(v.x); o[1] = (short)f2bf(v.y);
  o[2] = (short)f2bf(v.z); o[3] = (short)f2bf(v.w);
  ((short4v*)Wg1)[i] = o;
}

__global__ __launch_bounds__(256) void k_pack_g2(const float* __restrict__ Wih2,
    const float* __restrict__ Whh2, unsigned short* __restrict__ Wg2) {
  int i = blockIdx.x * 256 + threadIdx.x;            // 4096*1536 vec4
  if (i >= 4096 * 1536) return;
  int row = i / 1536, c4 = i - row * 1536;
  const float* src = (c4 < 1280) ? Wih2 + (size_t)row * 5120 + c4 * 4
                                 : Whh2 + (size_t)row * 1024 + (c4 - 1280) * 4;
  float4 v = *(const float4*)src;
  short4v o; o[0] = (short)f2bf(v.x); o[1] = (short)f2bf(v.y);
  o[2] = (short)f2bf(v.z); o[3] = (short)f2bf(v.w);
  ((short4v*)Wg2)[i] = o;
}

// --------------------------- phase-A helper kernels ------------------------
__global__ __launch_bounds__(256) void k_ximg(const float* __restrict__ src,
                                              unsigned short* __restrict__ dst) {
  int idx = blockIdx.x * 256 + threadIdx.x;          // 1568*4096
  int row = idx >> 12;
  dst[idx] = (row < 1500) ? f2bf(src[idx]) : (unsigned short)0;
}

__global__ __launch_bounds__(256) void k_mean(const float* __restrict__ img,
                                              unsigned short* __restrict__ dst) {
  int idx = blockIdx.x * 256 + threadIdx.x;          // 112*4096
  int b = idx >> 12, f = idx & 4095;
  unsigned short r = 0;
  if (b < 100) {
    float s = 0.f;
    for (int rr = 0; rr < 15; ++rr) s += img[((size_t)b * 15 + rr) * 4096 + f];
    r = f2bf(s * (1.f / 15.f));
  }
  dst[idx] = r;
}

__global__ __launch_bounds__(256) void k_reduce(const float* __restrict__ P,
    long long ss, int nslots, const float* __restrict__ bias, int colmask,
    float* __restrict__ out, int total) {
  int idx = blockIdx.x * 256 + threadIdx.x;
  if (idx >= total) return;
  float s = bias ? bias[idx & colmask] : 0.f;
  for (int sl = 0; sl < nslots; ++sl) s += P[(size_t)sl * ss + idx];
  out[idx] = s;
}

__global__ __launch_bounds__(512) void k_conv(const float* __restrict__ lin,
    const float* __restrict__ cw, const float* __restrict__ cb,
    float* __restrict__ topics) {
  int b = blockIdx.x;
  __shared__ float L[15 * 1024];
  for (int i = threadIdx.x; i < 15 * 1024; i += 512) L[i] = lin[(size_t)b * 15360 + i];
  __syncthreads();
  for (int idx = threadIdx.x; idx < 2500; idx += 512) {
    int tt = idx / 500, w = idx - tt * 500;
    float s = cb[tt];
    for (int kh = 0; kh < 15; ++kh) {
      const float* lr = &L[kh * 1024 + 2 * w];
      const float* wr = &cw[(tt * 15 + kh) * 26];
#pragma unroll
      for (int kw = 0; kw < 26; ++kw) s += lr[kw] * wr[kw];
    }
    topics[(size_t)b * 2500 + idx] = s;
  }
}

__global__ __launch_bounds__(256) void k_ttop(const float* __restrict__ topics,
    const float* __restrict__ Wt, const float* __restrict__ btp,
    float* __restrict__ ttop) {
  int idx = blockIdx.x * 256 + threadIdx.x;          // 500*512
  int r = idx >> 9, n = idx & 511;
  const float4* tr = (const float4*)(topics + (size_t)r * 500);
  const float4* wr = (const float4*)(Wt + (size_t)n * 500);
  float s = btp[n];
  for (int k = 0; k < 125; ++k) {
    float4 a = tr[k], w = wr[k];
    s += a.x * w.x + a.y * w.y + a.z * w.z + a.w * w.w;
  }
  ttop[idx] = s;
}

__global__ void k_words(const int* __restrict__ caps, const int* __restrict__ lens,
                        int* __restrict__ words, float* __restrict__ out3) {
  int idx = blockIdx.x * 256 + threadIdx.x;
  if (idx >= 500) return;
  int len = lens[idx];
  words[idx] = caps[idx * 52 + len - 1];
  out3[idx] = (float)(len - 1);
}

__global__ void k_caps(const int* __restrict__ caps, float* __restrict__ out2) {
  int idx = blockIdx.x * 256 + threadIdx.x;
  if (idx < 26000) out2[idx] = (float)caps[idx];
}

__global__ __launch_bounds__(256) void k_gather(const float* __restrict__ emb,
    const int* __restrict__ words, unsigned short* __restrict__ Xemb) {
  int idx = blockIdx.x * 256 + threadIdx.x;          // 560*1024
  int bt = idx >> 10, e = idx & 1023;
  Xemb[idx] = (bt < 500) ? f2bf(emb[(size_t)words[bt] * 1024 + e]) : (unsigned short)0;
}

__global__ __launch_bounds__(256) void k_gbase1(const float* __restrict__ P,
    const float* __restrict__ bih, const float* __restrict__ bhh,
    float* __restrict__ gb) {
  int idx = blockIdx.x * 256 + threadIdx.x;          // 112*4096
  int m = idx >> 12, n = idx & 4095;
  float s = bih[n] + bhh[n];
#pragma unroll
  for (int sl = 0; sl < 8; ++sl) s += P[((size_t)sl * 112 + m) * 4096 + n];
  gb[idx] = s;
}

// ------------------------------ per-step kernels ---------------------------
__global__ __launch_bounds__(256) void k_lstm1(const float* __restrict__ P,
    const float* __restrict__ gb1, const float* __restrict__ gemb, int t,
    float* __restrict__ c1, unsigned short* __restrict__ Xh1,
    unsigned short* __restrict__ X1, unsigned short* __restrict__ X2) {
  int idx = blockIdx.x * 256 + threadIdx.x;          // 100*1024
  int b = idx >> 10, j = idx & 1023;
  float g[4];
#pragma unroll
  for (int x = 0; x < 4; ++x) {
    int col = (x << 10) + j;
    float s = gb1[b * 4096 + col] + gemb[((size_t)b * 5 + t) * 4096 + col];
#pragma unroll
    for (int sl = 0; sl < 8; ++sl) s += P[((size_t)sl * 112 + b) * 4096 + col];
    g[x] = s;
  }
  float c = sigm(g[1]) * c1[idx] + sigm(g[0]) * tanhf(g[2]);
  float h = sigm(g[3]) * tanhf(c);
  c1[idx] = c;
  unsigned short hb = f2bf(h);
  Xh1[idx] = hb;
  X1[b * 2048 + 1024 + j] = hb;
  X2[(size_t)b * 6144 + 4096 + j] = hb;
}

__global__ __launch_bounds__(256) void k_att(const float* __restrict__ att1,
    const float* __restrict__ padec, const float* __restrict__ bdec,
    const float* __restrict__ ttop, const float* __restrict__ wfull,
    const float* __restrict__ bfull, int t, float* __restrict__ scores) {
  int wid = (blockIdx.x * 256 + threadIdx.x) >> 6;   // (b,r) pair
  int lane = threadIdx.x & 63;
  if (wid >= 1500) return;
  int b = wid / 15;
  const float* a1 = att1 + (size_t)wid * 512;
  const float* tp = ttop + ((size_t)b * 5 + t) * 512;
  float s = 0.f;
#pragma unroll
  for (int j = 0; j < 8; ++j) {
    int n = lane * 8 + j;
    float ad = bdec[n] + padec[(size_t)b * 512 + n]
             + padec[(size_t)(112 + b) * 512 + n]
             + padec[(size_t)(224 + b) * 512 + n]
             + padec[(size_t)(336 + b) * 512 + n];
    float v = a1[n] + ad + tp[n];
    s += fmaxf(v, 0.f) * wfull[n];
  }
#pragma unroll
  for (int o = 32; o; o >>= 1) s += __shfl_down(s, o, 64);
  if (lane == 0) scores[wid] = s + bfull[0];
}

__global__ __launch_bounds__(256) void k_softawe(const float* __restrict__ scores,
    const unsigned short* __restrict__ Ximg, unsigned short* __restrict__ X2) {
  int b = blockIdx.x;
  __shared__ float al[16];
  if (threadIdx.x == 0) {
    float m = -1e30f;
    for (int r = 0; r < 15; ++r) m = fmaxf(m, scores[b * 15 + r]);
    float e[15]; float sum = 0.f;
    for (int r = 0; r < 15; ++r) { e[r] = expf(scores[b * 15 + r] - m); sum += e[r]; }
    float inv = 1.f / sum;
    for (int r = 0; r < 15; ++r) al[r] = e[r] * inv;
  }
  __syncthreads();
  for (int f = threadIdx.x; f < 4096; f += 256) {
    float s = 0.f;
#pragma unroll
    for (int r = 0; r < 15; ++r) s += al[r] * bf2f(Ximg[((size_t)b * 15 + r) * 4096 + f]);
    X2[(size_t)b * 6144 + f] = f2bf(s);
  }
}

__global__ __launch_bounds__(256) void k_lstm2(const float* __restrict__ P,
    const float* __restrict__ bih, const float* __restrict__ bhh,
    float* __restrict__ c2, unsigned short* __restrict__ Xh2,
    unsigned short* __restrict__ X1, unsigned short* __restrict__ X2) {
  int idx = blockIdx.x * 256 + threadIdx.x;          // 100*1024
  int b = idx >> 10, j = idx & 1023;
  float g[4];
#pragma unroll
  for (int x = 0; x < 4; ++x) {
    int col = (x << 10) + j;
    float s = bih[col] + bhh[col];
#pragma unroll
    for (int sl = 0; sl < 12; ++sl) s += P[((size_t)sl * 112 + b) * 4096 + col];
    g[x] = s;
  }
  float c = sigm(g[1]) * c2[idx] + sigm(g[0]) * tanhf(g[2]);
  float h = sigm(g[3]) * tanhf(c);
  c2[idx] = c;
  unsigned short hb = f2bf(h);
  Xh2[idx] = hb;
  X1[b * 2048 + j] = hb;
  X2[(size_t)b * 6144 + 5120 + j] = hb;
}

__global__ __launch_bounds__(256) void k_eppred(const float* __restrict__ P,
    const float* __restrict__ bias, float* __restrict__ outp, int t) {
  int idx = blockIdx.x * 256 + threadIdx.x;          // 100*10000
  if (idx >= 1000000) return;
  int b = idx / 10000, v = idx - b * 10000;
  outp[((size_t)b * 5 + t) * 10000 + v] = bias[v]
      + P[(size_t)b * 10000 + v]         + P[(size_t)(112 + b) * 10000 + v]
      + P[(size_t)(224 + b) * 10000 + v] + P[(size_t)(336 + b) * 10000 + v];
}

// ---------------------------------------------------------------------------
extern "C" void kernel_launch(void* const* d_in, const int* in_sizes, int n_in,
                              void* d_out, int out_size, void* d_ws, size_t ws_size,
                              hipStream_t stream) {
  (void)in_sizes; (void)n_in; (void)out_size;
  const float* imgf  = (const float*)d_in[0];
  const int*   caps  = (const int*)d_in[1];
  const int*   lens  = (const int*)d_in[2];
  const float* W_lt  = (const float*)d_in[3];
  const float* b_lt  = (const float*)d_in[4];
  const float* convw = (const float*)d_in[5];
  const float* convb = (const float*)d_in[6];
  const float* W_feat = (const float*)d_in[7];
  const float* b_feat = (const float*)d_in[8];
  const float* W_dec = (const float*)d_in[9];
  const float* b_dec = (const float*)d_in[10];
  const float* W_top = (const float*)d_in[11];
  const float* b_top = (const float*)d_in[12];
  const float* W_full = (const float*)d_in[13];
  const float* b_full = (const float*)d_in[14];
  const float* emb   = (const float*)d_in[15];
  const float* W_ih1 = (const float*)d_in[16];
  const float* W_hh1 = (const float*)d_in[17];
  const float* b_ih1 = (const float*)d_in[18];
  const float* b_hh1 = (const float*)d_in[19];
  const float* W_ih2 = (const float*)d_in[20];
  const float* W_hh2 = (const float*)d_in[21];
  const float* b_ih2 = (const float*)d_in[22];
  const float* b_hh2 = (const float*)d_in[23];
  const float* W_fc1 = (const float*)d_in[24];
  const float* b_fc1 = (const float*)d_in[25];
  const float* W_fc  = (const float*)d_in[26];
  const float* b_fc  = (const float*)d_in[27];
  float* out = (float*)d_out;

  char* ws = (char*)d_ws;
  size_t off = 0;
  auto alloc = [&](size_t bytes) -> size_t {
    size_t o = off; off = (off + bytes + 255) & ~(size_t)255; return o;
  };
  const size_t oXimg  = alloc(1568ull * 4096 * 2);
  const size_t oXmean = alloc(112ull * 4096 * 2);
  const size_t oXemb  = alloc(560ull * 1024 * 2);
  const size_t oZERO  = off;                         // ---- zero block start
  const size_t oX1    = alloc(112ull * 2048 * 2);    // [h2 | h1] bf16
  const size_t oX2    = alloc(112ull * 6144 * 2);    // [awe | h1 | h2prev] bf16
  const size_t oXh1   = alloc(112ull * 1024 * 2);
  const size_t oXh2   = alloc(112ull * 1024 * 2);
  const size_t oc1    = alloc(100ull * 1024 * 4);
  const size_t oc2    = alloc(100ull * 1024 * 4);
  const size_t zeroBytes = off - oZERO;              // ---- zero block end
  const size_t olin   = alloc(1568ull * 1024 * 4);
  const size_t otop   = alloc(100ull * 2500 * 4);
  const size_t ottop  = alloc(500ull * 512 * 4);
  const size_t oatt1  = alloc(1568ull * 512 * 4);
  const size_t oscore = alloc(1536ull * 4);
  const size_t ogb1   = alloc(112ull * 4096 * 4);
  const size_t ogemb  = alloc(560ull * 4096 * 4);
  const size_t owords = alloc(512ull * 4);
  const size_t opg    = alloc(12ull * 112 * 4096 * 4);  // gate split-K partials
  const size_t opx    = alloc(8ull * 1568 * 512 * 4);   // phase-A partials / step partials (union)
  const size_t oWg1   = alloc(4096ull * 2048 * 2);      // [Wih1.h2 | Whh1] bf16
  const size_t oWg2   = alloc(4096ull * 6144 * 2);      // [Wih2 | Whh2] bf16
  const size_t oWfc1b = alloc(10000ull * 1024 * 2);
  const size_t oWfcb  = alloc(10000ull * 1024 * 2);
  const size_t oWdecb = alloc(512ull * 1024 * 2);
  const size_t oWltb  = alloc(1024ull * 4096 * 2);
  const size_t oWftb  = alloc(512ull * 4096 * 2);
  if (ws_size < off) return;  // insufficient scratch — loud fail

  unsigned short* Ximg  = (unsigned short*)(ws + oXimg);
  unsigned short* Xmean = (unsigned short*)(ws + oXmean);
  unsigned short* Xemb  = (unsigned short*)(ws + oXemb);
  unsigned short* X1    = (unsigned short*)(ws + oX1);
  unsigned short* X2    = (unsigned short*)(ws + oX2);
  unsigned short* Xh1   = (unsigned short*)(ws + oXh1);
  unsigned short* Xh2   = (unsigned short*)(ws + oXh2);
  float* c1    = (float*)(ws + oc1);
  float* c2    = (float*)(ws + oc2);
  float* lin   = (float*)(ws + olin);
  float* topics = (float*)(ws + otop);
  float* ttop  = (float*)(ws + ottop);
  float* att1  = (float*)(ws + oatt1);
  float* score = (float*)(ws + oscore);
  float* gb1   = (float*)(ws + ogb1);
  float* gemb  = (float*)(ws + ogemb);
  int*   words = (int*)(ws + owords);
  float* pg    = (float*)(ws + opg);
  float* px    = (float*)(ws + opx);
  unsigned short* Wg1   = (unsigned short*)(ws + oWg1);
  unsigned short* Wg2   = (unsigned short*)(ws + oWg2);
  unsigned short* Wfc1b = (unsigned short*)(ws + oWfc1b);
  unsigned short* Wfcb  = (unsigned short*)(ws + oWfcb);
  unsigned short* Wdecb = (unsigned short*)(ws + oWdecb);
  unsigned short* Wltb  = (unsigned short*)(ws + oWltb);
  unsigned short* Wftb  = (unsigned short*)(ws + oWftb);

  const long long S4 = 112ll * 4096;   // gate partial slot stride
  const long long SA = 112ll * 512;    // adec partial slot stride
  const long long SP = 112ll * 10000;  // preds partial slot stride

  hipMemsetAsync(ws + oZERO, 0, zeroBytes, stream);

  // -------- phase A (once) --------
  k_ximg<<<25088, 256, 0, stream>>>(imgf, Ximg);
  k_mean<<<1792, 256, 0, stream>>>(imgf, Xmean);
  // bf16 weight packs (reused / multi-read weights)
  k_pack_g1<<<8192, 256, 0, stream>>>(W_ih1, W_hh1, Wg1);
  k_pack_g2<<<24576, 256, 0, stream>>>(W_ih2, W_hh2, Wg2);
  k_cvt4<<<10000, 256, 0, stream>>>(W_fc1, Wfc1b, 2560000);
  k_cvt4<<<10000, 256, 0, stream>>>(W_fc, Wfcb, 2560000);
  k_cvt4<<<512, 256, 0, stream>>>(W_dec, Wdecb, 131072);
  k_cvt4<<<4096, 256, 0, stream>>>(W_lt, Wltb, 1048576);
  k_cvt4<<<2048, 256, 0, stream>>>(W_feat, Wftb, 524288);
  // autoencoder linear: z=4 (Kchunk 1024)
  gemm_bb<32><<<dim3(16, 14, 4), 256, 0, stream>>>(Ximg, 4096, Wltb, 4096, 1024,
                                                   px, 1568ll * 1024);
  k_reduce<<<6272, 256, 0, stream>>>(px, 1568ll * 1024, 4, b_lt, 1023, lin, 1568 * 1024);
  k_conv<<<100, 512, 0, stream>>>(lin, convw, convb, topics);
  k_ttop<<<1000, 256, 0, stream>>>(topics, W_top, b_top, ttop);
  // att1 = img @ W_feat^T: z=8 (Kchunk 512)
  gemm_bb<16><<<dim3(8, 14, 8), 256, 0, stream>>>(Ximg, 4096, Wftb, 4096, 512,
                                                  px, 1568ll * 512);
  k_reduce<<<3136, 256, 0, stream>>>(px, 1568ll * 512, 8, b_feat, 511, att1, 1568 * 512);
  k_words<<<2, 256, 0, stream>>>(caps, lens, words, out + 10026000);
  k_caps<<<102, 256, 0, stream>>>(caps, out + 10000000);
  k_gather<<<2240, 256, 0, stream>>>(emb, words, Xemb);
  // img_mean panel of W_ih1 (cols 1024..5119, f32, one-time), z=8
  gemm_bt<16><<<dim3(64, 1, 8), 256, 0, stream>>>(Xmean, 4096, W_ih1 + 1024, 6144, 4096,
                                                  pg, S4);
  k_gbase1<<<1792, 256, 0, stream>>>(pg, b_ih1, b_hh1, gb1);
  // emb panel of W_ih1 (cols 5120..6143, f32, one-time), all 5 steps, z=2
  gemm_bt<16><<<dim3(64, 5, 2), 256, 0, stream>>>(Xemb, 1024, W_ih1 + 5120, 6144, 4096,
                                                  px, 560ll * 4096);
  k_reduce<<<8960, 256, 0, stream>>>(px, 560ll * 4096, 2, nullptr, 4095, gemb, 560 * 4096);

  // -------- recurrent steps --------
  for (int t = 0; t < 5; ++t) {
    // gates1 = Wg1 @ [h2|h1prev]: K=2048, z=8 (Kchunk 256)
    gemm_bb<8><<<dim3(64, 1, 8), 256, 0, stream>>>(X1, 2048, Wg1, 2048, 4096, pg, S4);
    k_lstm1<<<400, 256, 0, stream>>>(pg, gb1, gemb, t, c1, Xh1, X1, X2);
    // adec: K=1024, z=4
    gemm_bb<8><<<dim3(8, 1, 4), 256, 0, stream>>>(Xh1, 1024, Wdecb, 1024, 512, px, SA);
    k_att<<<375, 256, 0, stream>>>(att1, px, b_dec, ttop, W_full, b_full, t, score);
    k_softawe<<<100, 256, 0, stream>>>(score, Ximg, X2);
    // preds1: K=1024, z=4
    gemm_bb<8><<<dim3(157, 1, 4), 256, 0, stream>>>(Xh1, 1024, Wfc1b, 1024, 10000, px, SP);
    k_eppred<<<3907, 256, 0, stream>>>(px, b_fc1, out + 5000000, t);
    // gates2 = Wg2 @ [awe|h1|h2prev]: K=6144, z=12 (Kchunk 512)
    gemm_bb<16><<<dim3(64, 1, 12), 256, 0, stream>>>(X2, 6144, Wg2, 6144, 4096, pg, S4);
    k_lstm2<<<400, 256, 0, stream>>>(pg, b_ih2, b_hh2, c2, Xh2, X1, X2);
    // preds: K=1024, z=4
    gemm_bb<8><<<dim3(157, 1, 4), 256, 0, stream>>>(Xh2, 1024, Wfcb, 1024, 10000, px, SP);
    k_eppred<<<3907, 256, 0, stream>>>(px, b_fc, out, t);
  }
}

// Round 4
// 789.719 us; speedup vs baseline: 2.6857x; 1.6335x over previous
//
#include <hip/hip_runtime.h>

typedef __attribute__((ext_vector_type(8))) short short8;
typedef __attribute__((ext_vector_type(4))) short short4v;
typedef __attribute__((ext_vector_type(4))) float f32x4;

__device__ __forceinline__ unsigned short f2bf(float f) {
  unsigned int u = __float_as_uint(f);
  u += 0x7fffu + ((u >> 16) & 1u);   // RNE round to bf16
  return (unsigned short)(u >> 16);
}
__device__ __forceinline__ float bf2f(unsigned short u) {
  return __uint_as_float(((unsigned int)u) << 16);
}
__device__ __forceinline__ float sigm(float x) { return 1.f / (1.f + expf(-x)); }

// ---------------------------------------------------------------------------
// Skinny GEMM v5, bf16 weights. Per block: 112(M) x 64(N), K = NKC*256 per z.
// X staged to LDS in MFMA-fragment order (56 frags * 1KB = 57 KB); inner loop
// is an 8-deep W load burst + ds_read_b128 + MFMA. Partials written bf16.
//   C[z*ss + m*N + n] = sum_{k in chunk z} X[m][k] * W[n][k]
// ---------------------------------------------------------------------------
template<int NKC>
__global__ __launch_bounds__(256) void gemm_v5(
    const unsigned short* __restrict__ X, int ldx,
    const unsigned short* __restrict__ W, int ldw, int N,
    unsigned short* __restrict__ C, long long slotStride)
{
  __shared__ short8 lds[3584];                    // 57344 B
  const int tid = threadIdx.x;
  const int lane = tid & 63, wv = tid >> 6;
  const int l16 = lane & 15, kg = (lane >> 4) * 8;
  const int mbase = blockIdx.y * 112;
  const int ncol = blockIdx.x * 64 + wv * 16 + l16;
  const int nrow = (ncol < N) ? ncol : (N - 1);
  const long long k0 = (long long)blockIdx.z * (NKC * 256);
  C += (long long)blockIdx.z * slotStride;

  const unsigned short* wp = W + (size_t)nrow * ldw + kg + k0;
  const unsigned short* xb = X + (size_t)(mbase + l16) * ldx + kg + k0;
  const size_t xrow = (size_t)16 * ldx;

  f32x4 acc[7];
#pragma unroll
  for (int i = 0; i < 7; ++i) acc[i] = (f32x4){0.f, 0.f, 0.f, 0.f};

  for (int kc = 0; kc < NKC; ++kc) {
    if (kc) __syncthreads();
    // W burst for this chunk (8 independent 16B loads, in flight during stage)
    short8 wbuf[8];
#pragma unroll
    for (int ks = 0; ks < 8; ++ks)
      wbuf[ks] = *(const short8*)(wp + kc * 256 + ks * 32);
    // stage X chunk into LDS, fragment-major
    short8 xst[14];
#pragma unroll
    for (int i = 0; i < 14; ++i) {
      const int f = wv + i * 4, mt = f >> 3, ks = f & 7;
      xst[i] = *(const short8*)(xb + (size_t)mt * xrow + kc * 256 + ks * 32);
    }
#pragma unroll
    for (int i = 0; i < 14; ++i) lds[(wv + i * 4) * 64 + lane] = xst[i];
    __syncthreads();
#pragma unroll
    for (int ks = 0; ks < 8; ++ks)
#pragma unroll
      for (int mt = 0; mt < 7; ++mt) {
        short8 a = lds[(mt * 8 + ks) * 64 + lane];
        acc[mt] = __builtin_amdgcn_mfma_f32_16x16x32_bf16(a, wbuf[ks], acc[mt], 0, 0, 0);
      }
  }
  if (ncol < N) {
    const int r0 = (lane >> 4) * 4;
#pragma unroll
    for (int mt = 0; mt < 7; ++mt)
#pragma unroll
      for (int r = 0; r < 4; ++r)
        C[(size_t)(mbase + mt * 16 + r0 + r) * N + ncol] = f2bf(acc[mt][r]);
  }
}

// Same, f32 weights (one-time-use W_ih1 panels), converted in-register.
template<int NKC>
__global__ __launch_bounds__(256) void gemm_v5f(
    const unsigned short* __restrict__ X, int ldx,
    const float* __restrict__ W, int ldw, int N,
    unsigned short* __restrict__ C, long long slotStride)
{
  __shared__ short8 lds[3584];
  const int tid = threadIdx.x;
  const int lane = tid & 63, wv = tid >> 6;
  const int l16 = lane & 15, kg = (lane >> 4) * 8;
  const int mbase = blockIdx.y * 112;
  const int ncol = blockIdx.x * 64 + wv * 16 + l16;
  const int nrow = (ncol < N) ? ncol : (N - 1);
  const long long k0 = (long long)blockIdx.z * (NKC * 256);
  C += (long long)blockIdx.z * slotStride;

  const float* wp = W + (size_t)nrow * ldw + kg + k0;
  const unsigned short* xb = X + (size_t)(mbase + l16) * ldx + kg + k0;
  const size_t xrow = (size_t)16 * ldx;

  f32x4 acc[7];
#pragma unroll
  for (int i = 0; i < 7; ++i) acc[i] = (f32x4){0.f, 0.f, 0.f, 0.f};

  for (int kc = 0; kc < NKC; ++kc) {
    if (kc) __syncthreads();
    float4 wa[8], wb[8];
#pragma unroll
    for (int ks = 0; ks < 8; ++ks) {
      wa[ks] = *(const float4*)(wp + kc * 256 + ks * 32);
      wb[ks] = *(const float4*)(wp + kc * 256 + ks * 32 + 4);
    }
    short8 xst[14];
#pragma unroll
    for (int i = 0; i < 14; ++i) {
      const int f = wv + i * 4, mt = f >> 3, ks = f & 7;
      xst[i] = *(const short8*)(xb + (size_t)mt * xrow + kc * 256 + ks * 32);
    }
#pragma unroll
    for (int i = 0; i < 14; ++i) lds[(wv + i * 4) * 64 + lane] = xst[i];
    __syncthreads();
#pragma unroll
    for (int ks = 0; ks < 8; ++ks) {
      short8 w;
      w[0] = (short)f2bf(wa[ks].x); w[1] = (short)f2bf(wa[ks].y);
      w[2] = (short)f2bf(wa[ks].z); w[3] = (short)f2bf(wa[ks].w);
      w[4] = (short)f2bf(wb[ks].x); w[5] = (short)f2bf(wb[ks].y);
      w[6] = (short)f2bf(wb[ks].z); w[7] = (short)f2bf(wb[ks].w);
#pragma unroll
      for (int mt = 0; mt < 7; ++mt) {
        short8 a = lds[(mt * 8 + ks) * 64 + lane];
        acc[mt] = __builtin_amdgcn_mfma_f32_16x16x32_bf16(a, w, acc[mt], 0, 0, 0);
      }
    }
  }
  if (ncol < N) {
    const int r0 = (lane >> 4) * 4;
#pragma unroll
    for (int mt = 0; mt < 7; ++mt)
#pragma unroll
      for (int r = 0; r < 4; ++r)
        C[(size_t)(mbase + mt * 16 + r0 + r) * N + ncol] = f2bf(acc[mt][r]);
  }
}

// --------------------------- weight pack/convert ---------------------------
__global__ __launch_bounds__(256) void k_cvt4(const float* __restrict__ src,
                                              unsigned short* __restrict__ dst, int n4) {
  int i = blockIdx.x * 256 + threadIdx.x;
  if (i >= n4) return;
  float4 v = ((const float4*)src)[i];
  short4v o; o[0] = (short)f2bf(v.x); o[1] = (short)f2bf(v.y);
  o[2] = (short)f2bf(v.z); o[3] = (short)f2bf(v.w);
  ((short4v*)dst)[i] = o;
}

__global__ __launch_bounds__(256) void k_pack_g1(const float* __restrict__ Wih1,
    const float* __restrict__ Whh1, unsigned short* __restrict__ Wg1) {
  int i = blockIdx.x * 256 + threadIdx.x;            // 4096*512 vec4
  if (i >= 4096 * 512) return;
  int row = i >> 9, c4 = i & 511;
  const float* src = (c4 < 256) ? Wih1 + (size_t)row * 6144 + c4 * 4
                                : Whh1 + (size_t)row * 1024 + (c4 - 256) * 4;
  float4 v = *(const float4*)src;
  short4v o; o[0] = (short)f2bf(v.x); o[1] = (short)f2bf(v.y);
  o[2] = (short)f2bf(v.z); o[3] = (short)f2bf(v.w);
  ((short4v*)Wg1)[i] = o;
}

__global__ __launch_bounds__(256) void k_pack_g2(const float* __restrict__ Wih2,
    const float* __restrict__ Whh2, unsigned short* __restrict__ Wg2) {
  int i = blockIdx.x * 256 + threadIdx.x;            // 4096*1536 vec4
  if (i >= 4096 * 1536) return;
  int row = i / 1536, c4 = i - row * 1536;
  const float* src = (c4 < 1280) ? Wih2 + (size_t)row * 5120 + c4 * 4
                                 : Whh2 + (size_t)row * 1024 + (c4 - 1280) * 4;
  float4 v = *(const float4*)src;
  short4v o; o[0] = (short)f2bf(v.x); o[1] = (short)f2bf(v.y);
  o[2] = (short)f2bf(v.z); o[3] = (short)f2bf(v.w);
  ((short4v*)Wg2)[i] = o;
}

// --------------------------- phase-A helper kernels ------------------------
__global__ __launch_bounds__(256) void k_ximg(const float* __restrict__ src,
                                              unsigned short* __restrict__ dst) {
  int idx = blockIdx.x * 256 + threadIdx.x;          // 1568*4096
  int row = idx >> 12;
  dst[idx] = (row < 1500) ? f2bf(src[idx]) : (unsigned short)0;
}

__global__ __launch_bounds__(256) void k_mean(const float* __restrict__ img,
                                              unsigned short* __restrict__ dst) {
  int idx = blockIdx.x * 256 + threadIdx.x;          // 112*4096
  int b = idx >> 12, f = idx & 4095;
  unsigned short r = 0;
  if (b < 100) {
    float s = 0.f;
    for (int rr = 0; rr < 15; ++rr) s += img[((size_t)b * 15 + rr) * 4096 + f];
    r = f2bf(s * (1.f / 15.f));
  }
  dst[idx] = r;
}

__global__ __launch_bounds__(256) void k_reduce(const unsigned short* __restrict__ P,
    long long ss, int nslots, const float* __restrict__ bias, int colmask,
    float* __restrict__ out, int total) {
  int idx = blockIdx.x * 256 + threadIdx.x;
  if (idx >= total) return;
  float s = bias ? bias[idx & colmask] : 0.f;
  for (int sl = 0; sl < nslots; ++sl) s += bf2f(P[(size_t)sl * ss + idx]);
  out[idx] = s;
}

__global__ __launch_bounds__(512) void k_conv(const float* __restrict__ lin,
    const float* __restrict__ cw, const float* __restrict__ cb,
    float* __restrict__ topics) {
  int b = blockIdx.x;
  __shared__ float L[15 * 1024];
  for (int i = threadIdx.x; i < 15 * 1024; i += 512) L[i] = lin[(size_t)b * 15360 + i];
  __syncthreads();
  for (int idx = threadIdx.x; idx < 2500; idx += 512) {
    int tt = idx / 500, w = idx - tt * 500;
    float s = cb[tt];
    for (int kh = 0; kh < 15; ++kh) {
      const float* lr = &L[kh * 1024 + 2 * w];
      const float* wr = &cw[(tt * 15 + kh) * 26];
#pragma unroll
      for (int kw = 0; kw < 26; ++kw) s += lr[kw] * wr[kw];
    }
    topics[(size_t)b * 2500 + idx] = s;
  }
}

__global__ __launch_bounds__(256) void k_ttop(const float* __restrict__ topics,
    const float* __restrict__ Wt, const float* __restrict__ btp,
    float* __restrict__ ttop) {
  int idx = blockIdx.x * 256 + threadIdx.x;          // 500*512
  int r = idx >> 9, n = idx & 511;
  const float4* tr = (const float4*)(topics + (size_t)r * 500);
  const float4* wr = (const float4*)(Wt + (size_t)n * 500);
  float s = btp[n];
  for (int k = 0; k < 125; ++k) {
    float4 a = tr[k], w = wr[k];
    s += a.x * w.x + a.y * w.y + a.z * w.z + a.w * w.w;
  }
  ttop[idx] = s;
}

__global__ void k_words(const int* __restrict__ caps, const int* __restrict__ lens,
                        int* __restrict__ words, float* __restrict__ out3) {
  int idx = blockIdx.x * 256 + threadIdx.x;
  if (idx >= 500) return;
  int len = lens[idx];
  words[idx] = caps[idx * 52 + len - 1];
  out3[idx] = (float)(len - 1);
}

__global__ void k_caps(const int* __restrict__ caps, float* __restrict__ out2) {
  int idx = blockIdx.x * 256 + threadIdx.x;
  if (idx < 26000) out2[idx] = (float)caps[idx];
}

__global__ __launch_bounds__(256) void k_gather(const float* __restrict__ emb,
    const int* __restrict__ words, unsigned short* __restrict__ Xemb) {
  int idx = blockIdx.x * 256 + threadIdx.x;          // 560*1024
  int bt = idx >> 10, e = idx & 1023;
  Xemb[idx] = (bt < 500) ? f2bf(emb[(size_t)words[bt] * 1024 + e]) : (unsigned short)0;
}

__global__ __launch_bounds__(256) void k_gbase1(const unsigned short* __restrict__ P,
    const float* __restrict__ bih, const float* __restrict__ bhh,
    float* __restrict__ gb) {
  int idx = blockIdx.x * 256 + threadIdx.x;          // 112*4096
  int m = idx >> 12, n = idx & 4095;
  float s = bih[n] + bhh[n];
#pragma unroll
  for (int sl = 0; sl < 8; ++sl) s += bf2f(P[((size_t)sl * 112 + m) * 4096 + n]);
  gb[idx] = s;
}

// ------------------------------ per-step kernels ---------------------------
__global__ __launch_bounds__(256) void k_lstm1(const unsigned short* __restrict__ P,
    const float* __restrict__ gb1, const float* __restrict__ gemb, int t,
    float* __restrict__ c1, unsigned short* __restrict__ Xh1,
    unsigned short* __restrict__ X1, unsigned short* __restrict__ X2) {
  int idx = blockIdx.x * 256 + threadIdx.x;          // 100*1024
  int b = idx >> 10, j = idx & 1023;
  float g[4];
#pragma unroll
  for (int x = 0; x < 4; ++x) {
    int col = (x << 10) + j;
    float s = gb1[b * 4096 + col] + gemb[((size_t)b * 5 + t) * 4096 + col];
#pragma unroll
    for (int sl = 0; sl < 8; ++sl) s += bf2f(P[((size_t)sl * 112 + b) * 4096 + col]);
    g[x] = s;
  }
  float c = sigm(g[1]) * c1[idx] + sigm(g[0]) * tanhf(g[2]);
  float h = sigm(g[3]) * tanhf(c);
  c1[idx] = c;
  unsigned short hb = f2bf(h);
  Xh1[idx] = hb;
  X1[b * 2048 + 1024 + j] = hb;
  X2[(size_t)b * 6144 + 4096 + j] = hb;
}

__global__ __launch_bounds__(256) void k_att(const float* __restrict__ att1,
    const unsigned short* __restrict__ padec, const float* __restrict__ bdec,
    const float* __restrict__ ttop, const float* __restrict__ wfull,
    const float* __restrict__ bfull, int t, float* __restrict__ scores) {
  int wid = (blockIdx.x * 256 + threadIdx.x) >> 6;   // (b,r) pair
  int lane = threadIdx.x & 63;
  if (wid >= 1500) return;
  int b = wid / 15;
  const float* a1 = att1 + (size_t)wid * 512;
  const float* tp = ttop + ((size_t)b * 5 + t) * 512;
  float s = 0.f;
#pragma unroll
  for (int j = 0; j < 8; ++j) {
    int n = lane * 8 + j;
    float ad = bdec[n] + bf2f(padec[(size_t)b * 512 + n])
             + bf2f(padec[(size_t)(112 + b) * 512 + n])
             + bf2f(padec[(size_t)(224 + b) * 512 + n])
             + bf2f(padec[(size_t)(336 + b) * 512 + n]);
    float v = a1[n] + ad + tp[n];
    s += fmaxf(v, 0.f) * wfull[n];
  }
#pragma unroll
  for (int o = 32; o; o >>= 1) s += __shfl_down(s, o, 64);
  if (lane == 0) scores[wid] = s + bfull[0];
}

__global__ __launch_bounds__(256) void k_softawe(const float* __restrict__ scores,
    const unsigned short* __restrict__ Ximg, unsigned short* __restrict__ X2) {
  int b = blockIdx.x;
  __shared__ float al[16];
  if (threadIdx.x == 0) {
    float m = -1e30f;
    for (int r = 0; r < 15; ++r) m = fmaxf(m, scores[b * 15 + r]);
    float e[15]; float sum = 0.f;
    for (int r = 0; r < 15; ++r) { e[r] = expf(scores[b * 15 + r] - m); sum += e[r]; }
    float inv = 1.f / sum;
    for (int r = 0; r < 15; ++r) al[r] = e[r] * inv;
  }
  __syncthreads();
  for (int f = threadIdx.x; f < 4096; f += 256) {
    float s = 0.f;
#pragma unroll
    for (int r = 0; r < 15; ++r) s += al[r] * bf2f(Ximg[((size_t)b * 15 + r) * 4096 + f]);
    X2[(size_t)b * 6144 + f] = f2bf(s);
  }
}

__global__ __launch_bounds__(256) void k_lstm2(const unsigned short* __restrict__ P,
    const float* __restrict__ bih, const float* __restrict__ bhh,
    float* __restrict__ c2, unsigned short* __restrict__ Xh2,
    unsigned short* __restrict__ X1, unsigned short* __restrict__ X2) {
  int idx = blockIdx.x * 256 + threadIdx.x;          // 100*1024
  int b = idx >> 10, j = idx & 1023;
  float g[4];
#pragma unroll
  for (int x = 0; x < 4; ++x) {
    int col = (x << 10) + j;
    float s = bih[col] + bhh[col];
#pragma unroll
    for (int sl = 0; sl < 12; ++sl) s += bf2f(P[((size_t)sl * 112 + b) * 4096 + col]);
    g[x] = s;
  }
  float c = sigm(g[1]) * c2[idx] + sigm(g[0]) * tanhf(g[2]);
  float h = sigm(g[3]) * tanhf(c);
  c2[idx] = c;
  unsigned short hb = f2bf(h);
  Xh2[idx] = hb;
  X1[b * 2048 + j] = hb;
  X2[(size_t)b * 6144 + 5120 + j] = hb;
}

__global__ __launch_bounds__(256) void k_eppred(const unsigned short* __restrict__ P,
    const float* __restrict__ bias, float* __restrict__ outp, int t) {
  int idx = blockIdx.x * 256 + threadIdx.x;          // 100*10000
  if (idx >= 1000000) return;
  int b = idx / 10000, v = idx - b * 10000;
  outp[((size_t)b * 5 + t) * 10000 + v] = bias[v]
      + bf2f(P[(size_t)b * 10000 + v])         + bf2f(P[(size_t)(112 + b) * 10000 + v])
      + bf2f(P[(size_t)(224 + b) * 10000 + v]) + bf2f(P[(size_t)(336 + b) * 10000 + v]);
}

// ---------------------------------------------------------------------------
extern "C" void kernel_launch(void* const* d_in, const int* in_sizes, int n_in,
                              void* d_out, int out_size, void* d_ws, size_t ws_size,
                              hipStream_t stream) {
  (void)in_sizes; (void)n_in; (void)out_size;
  const float* imgf  = (const float*)d_in[0];
  const int*   caps  = (const int*)d_in[1];
  const int*   lens  = (const int*)d_in[2];
  const float* W_lt  = (const float*)d_in[3];
  const float* b_lt  = (const float*)d_in[4];
  const float* convw = (const float*)d_in[5];
  const float* convb = (const float*)d_in[6];
  const float* W_feat = (const float*)d_in[7];
  const float* b_feat = (const float*)d_in[8];
  const float* W_dec = (const float*)d_in[9];
  const float* b_dec = (const float*)d_in[10];
  const float* W_top = (const float*)d_in[11];
  const float* b_top = (const float*)d_in[12];
  const float* W_full = (const float*)d_in[13];
  const float* b_full = (const float*)d_in[14];
  const float* emb   = (const float*)d_in[15];
  const float* W_ih1 = (const float*)d_in[16];
  const float* W_hh1 = (const float*)d_in[17];
  const float* b_ih1 = (const float*)d_in[18];
  const float* b_hh1 = (const float*)d_in[19];
  const float* W_ih2 = (const float*)d_in[20];
  const float* W_hh2 = (const float*)d_in[21];
  const float* b_ih2 = (const float*)d_in[22];
  const float* b_hh2 = (const float*)d_in[23];
  const float* W_fc1 = (const float*)d_in[24];
  const float* b_fc1 = (const float*)d_in[25];
  const float* W_fc  = (const float*)d_in[26];
  const float* b_fc  = (const float*)d_in[27];
  float* out = (float*)d_out;

  char* ws = (char*)d_ws;
  size_t off = 0;
  auto alloc = [&](size_t bytes) -> size_t {
    size_t o = off; off = (off + bytes + 255) & ~(size_t)255; return o;
  };
  const size_t oXimg  = alloc(1568ull * 4096 * 2);
  const size_t oXmean = alloc(112ull * 4096 * 2);
  const size_t oXemb  = alloc(560ull * 1024 * 2);
  const size_t oZERO  = off;                         // ---- zero block start
  const size_t oX1    = alloc(112ull * 2048 * 2);    // [h2 | h1] bf16
  const size_t oX2    = alloc(112ull * 6144 * 2);    // [awe | h1 | h2prev] bf16
  const size_t oXh1   = alloc(112ull * 1024 * 2);
  const size_t oXh2   = alloc(112ull * 1024 * 2);
  const size_t oc1    = alloc(100ull * 1024 * 4);
  const size_t oc2    = alloc(100ull * 1024 * 4);
  const size_t zeroBytes = off - oZERO;              // ---- zero block end
  const size_t olin   = alloc(1568ull * 1024 * 4);
  const size_t otop   = alloc(100ull * 2500 * 4);
  const size_t ottop  = alloc(500ull * 512 * 4);
  const size_t oatt1  = alloc(1568ull * 512 * 4);
  const size_t oscore = alloc(1536ull * 4);
  const size_t ogb1   = alloc(112ull * 4096 * 4);
  const size_t ogemb  = alloc(560ull * 4096 * 4);
  const size_t owords = alloc(512ull * 4);
  const size_t opg    = alloc(12ull * 112 * 4096 * 2);  // gate partials (bf16)
  const size_t opx    = alloc(4ull * 1568 * 1024 * 2);  // shared partials (bf16)
  const size_t oWg1   = alloc(4096ull * 2048 * 2);      // [Wih1.h2 | Whh1] bf16
  const size_t oWg2   = alloc(4096ull * 6144 * 2);      // [Wih2 | Whh2] bf16
  const size_t oWfc1b = alloc(10000ull * 1024 * 2);
  const size_t oWfcb  = alloc(10000ull * 1024 * 2);
  const size_t oWdecb = alloc(512ull * 1024 * 2);
  const size_t oWltb  = alloc(1024ull * 4096 * 2);
  const size_t oWftb  = alloc(512ull * 4096 * 2);
  if (ws_size < off) return;  // insufficient scratch — loud fail

  unsigned short* Ximg  = (unsigned short*)(ws + oXimg);
  unsigned short* Xmean = (unsigned short*)(ws + oXmean);
  unsigned short* Xemb  = (unsigned short*)(ws + oXemb);
  unsigned short* X1    = (unsigned short*)(ws + oX1);
  unsigned short* X2    = (unsigned short*)(ws + oX2);
  unsigned short* Xh1   = (unsigned short*)(ws + oXh1);
  unsigned short* Xh2   = (unsigned short*)(ws + oXh2);
  float* c1    = (float*)(ws + oc1);
  float* c2    = (float*)(ws + oc2);
  float* lin   = (float*)(ws + olin);
  float* topics = (float*)(ws + otop);
  float* ttop  = (float*)(ws + ottop);
  float* att1  = (float*)(ws + oatt1);
  float* score = (float*)(ws + oscore);
  float* gb1   = (float*)(ws + ogb1);
  float* gemb  = (float*)(ws + ogemb);
  int*   words = (int*)(ws + owords);
  unsigned short* pg = (unsigned short*)(ws + opg);
  unsigned short* px = (unsigned short*)(ws + opx);
  unsigned short* Wg1   = (unsigned short*)(ws + oWg1);
  unsigned short* Wg2   = (unsigned short*)(ws + oWg2);
  unsigned short* Wfc1b = (unsigned short*)(ws + oWfc1b);
  unsigned short* Wfcb  = (unsigned short*)(ws + oWfcb);
  unsigned short* Wdecb = (unsigned short*)(ws + oWdecb);
  unsigned short* Wltb  = (unsigned short*)(ws + oWltb);
  unsigned short* Wftb  = (unsigned short*)(ws + oWftb);

  const long long S4 = 112ll * 4096;   // gate partial slot stride
  const long long SA = 112ll * 512;    // adec partial slot stride
  const long long SP = 112ll * 10000;  // preds partial slot stride

  hipMemsetAsync(ws + oZERO, 0, zeroBytes, stream);

  // -------- phase A (once) --------
  k_ximg<<<25088, 256, 0, stream>>>(imgf, Ximg);
  k_mean<<<1792, 256, 0, stream>>>(imgf, Xmean);
  k_pack_g1<<<8192, 256, 0, stream>>>(W_ih1, W_hh1, Wg1);
  k_pack_g2<<<24576, 256, 0, stream>>>(W_ih2, W_hh2, Wg2);
  k_cvt4<<<10000, 256, 0, stream>>>(W_fc1, Wfc1b, 2560000);
  k_cvt4<<<10000, 256, 0, stream>>>(W_fc, Wfcb, 2560000);
  k_cvt4<<<512, 256, 0, stream>>>(W_dec, Wdecb, 131072);
  k_cvt4<<<4096, 256, 0, stream>>>(W_lt, Wltb, 1048576);
  k_cvt4<<<2048, 256, 0, stream>>>(W_feat, Wftb, 524288);
  // autoencoder linear: K=4096 = 4z * (4 chunks * 256)
  gemm_v5<4><<<dim3(16, 14, 4), 256, 0, stream>>>(Ximg, 4096, Wltb, 4096, 1024,
                                                  px, 1568ll * 1024);
  k_reduce<<<6272, 256, 0, stream>>>(px, 1568ll * 1024, 4, b_lt, 1023, lin, 1568 * 1024);
  k_conv<<<100, 512, 0, stream>>>(lin, convw, convb, topics);
  k_ttop<<<1000, 256, 0, stream>>>(topics, W_top, b_top, ttop);
  // att1: K=4096 = 4z * 1024
  gemm_v5<4><<<dim3(8, 14, 4), 256, 0, stream>>>(Ximg, 4096, Wftb, 4096, 512,
                                                 px, 1568ll * 512);
  k_reduce<<<3136, 256, 0, stream>>>(px, 1568ll * 512, 4, b_feat, 511, att1, 1568 * 512);
  k_words<<<2, 256, 0, stream>>>(caps, lens, words, out + 10026000);
  k_caps<<<102, 256, 0, stream>>>(caps, out + 10000000);
  k_gather<<<2240, 256, 0, stream>>>(emb, words, Xemb);
  // img_mean panel of W_ih1 (f32, one-time): K=4096 = 8z * 512
  gemm_v5f<2><<<dim3(64, 1, 8), 256, 0, stream>>>(Xmean, 4096, W_ih1 + 1024, 6144, 4096,
                                                  pg, S4);
  k_gbase1<<<1792, 256, 0, stream>>>(pg, b_ih1, b_hh1, gb1);
  // emb panel of W_ih1 (f32, one-time): all 5 steps, K=1024 = 4z * 256
  gemm_v5f<1><<<dim3(64, 5, 4), 256, 0, stream>>>(Xemb, 1024, W_ih1 + 5120, 6144, 4096,
                                                  px, 560ll * 4096);
  k_reduce<<<8960, 256, 0, stream>>>(px, 560ll * 4096, 4, nullptr, 4095, gemb, 560 * 4096);

  // -------- recurrent steps --------
  for (int t = 0; t < 5; ++t) {
    // gates1 = Wg1 @ [h2|h1prev]: K=2048 = 8z * 256
    gemm_v5<1><<<dim3(64, 1, 8), 256, 0, stream>>>(X1, 2048, Wg1, 2048, 4096, pg, S4);
    k_lstm1<<<400, 256, 0, stream>>>(pg, gb1, gemb, t, c1, Xh1, X1, X2);
    // adec: K=1024 = 4z * 256
    gemm_v5<1><<<dim3(8, 1, 4), 256, 0, stream>>>(Xh1, 1024, Wdecb, 1024, 512, px, SA);
    k_att<<<375, 256, 0, stream>>>(att1, px, b_dec, ttop, W_full, b_full, t, score);
    k_softawe<<<100, 256, 0, stream>>>(score, Ximg, X2);
    // preds1: K=1024 = 4z * 256
    gemm_v5<1><<<dim3(157, 1, 4), 256, 0, stream>>>(Xh1, 1024, Wfc1b, 1024, 10000, px, SP);
    k_eppred<<<3907, 256, 0, stream>>>(px, b_fc1, out + 5000000, t);
    // gates2 = Wg2 @ [awe|h1|h2prev]: K=6144 = 12z * (2 chunks * 256)
    gemm_v5<2><<<dim3(64, 1, 12), 256, 0, stream>>>(X2, 6144, Wg2, 6144, 4096, pg, S4);
    k_lstm2<<<400, 256, 0, stream>>>(pg, b_ih2, b_hh2, c2, Xh2, X1, X2);
    // preds: K=1024 = 4z * 256
    gemm_v5<1><<<dim3(157, 1, 4), 256, 0, stream>>>(Xh2, 1024, Wfcb, 1024, 10000, px, SP);
    k_eppred<<<3907, 256, 0, stream>>>(px, b_fc, out, t);
  }
}

// Round 5
// 704.549 us; speedup vs baseline: 3.0103x; 1.1209x over previous
//
#include <hip/hip_runtime.h>

typedef __attribute__((ext_vector_type(8))) short short8;
typedef __attribute__((ext_vector_type(4))) short short4v;
typedef __attribute__((ext_vector_type(4))) float f32x4;

__device__ __forceinline__ unsigned short f2bf(float f) {
  unsigned int u = __float_as_uint(f);
  u += 0x7fffu + ((u >> 16) & 1u);   // RNE round to bf16
  return (unsigned short)(u >> 16);
}
__device__ __forceinline__ float bf2f(unsigned short u) {
  return __uint_as_float(((unsigned int)u) << 16);
}
__device__ __forceinline__ float sigm(float x) { return 1.f / (1.f + expf(-x)); }

// ---------------------------------------------------------------------------
// Skinny GEMM, bf16 weights. Per block: 112(M) x 64(N), K = NKC*256 per z.
// X staged to LDS in MFMA-fragment order; inner loop = 8-deep W load burst +
// ds_read_b128 + MFMA. Partials written bf16.
// ---------------------------------------------------------------------------
template<int NKC>
__global__ __launch_bounds__(256) void gemm_v5(
    const unsigned short* __restrict__ X, int ldx,
    const unsigned short* __restrict__ W, int ldw, int N,
    unsigned short* __restrict__ C, long long slotStride)
{
  __shared__ short8 lds[3584];                    // 57344 B
  const int tid = threadIdx.x;
  const int lane = tid & 63, wv = tid >> 6;
  const int l16 = lane & 15, kg = (lane >> 4) * 8;
  const int mbase = blockIdx.y * 112;
  const int ncol = blockIdx.x * 64 + wv * 16 + l16;
  const int nrow = (ncol < N) ? ncol : (N - 1);
  const long long k0 = (long long)blockIdx.z * (NKC * 256);
  C += (long long)blockIdx.z * slotStride;

  const unsigned short* wp = W + (size_t)nrow * ldw + kg + k0;
  const unsigned short* xb = X + (size_t)(mbase + l16) * ldx + kg + k0;
  const size_t xrow = (size_t)16 * ldx;

  f32x4 acc[7];
#pragma unroll
  for (int i = 0; i < 7; ++i) acc[i] = (f32x4){0.f, 0.f, 0.f, 0.f};

  for (int kc = 0; kc < NKC; ++kc) {
    if (kc) __syncthreads();
    short8 wbuf[8];
#pragma unroll
    for (int ks = 0; ks < 8; ++ks)
      wbuf[ks] = *(const short8*)(wp + kc * 256 + ks * 32);
    short8 xst[14];
#pragma unroll
    for (int i = 0; i < 14; ++i) {
      const int f = wv + i * 4, mt = f >> 3, ks = f & 7;
      xst[i] = *(const short8*)(xb + (size_t)mt * xrow + kc * 256 + ks * 32);
    }
#pragma unroll
    for (int i = 0; i < 14; ++i) lds[(wv + i * 4) * 64 + lane] = xst[i];
    __syncthreads();
#pragma unroll
    for (int ks = 0; ks < 8; ++ks)
#pragma unroll
      for (int mt = 0; mt < 7; ++mt) {
        short8 a = lds[(mt * 8 + ks) * 64 + lane];
        acc[mt] = __builtin_amdgcn_mfma_f32_16x16x32_bf16(a, wbuf[ks], acc[mt], 0, 0, 0);
      }
  }
  if (ncol < N) {
    const int r0 = (lane >> 4) * 4;
#pragma unroll
    for (int mt = 0; mt < 7; ++mt)
#pragma unroll
      for (int r = 0; r < 4; ++r)
        C[(size_t)(mbase + mt * 16 + r0 + r) * N + ncol] = f2bf(acc[mt][r]);
  }
}

// Same, f32 weights (one-time-use W_ih1 panels), converted in-register.
template<int NKC>
__global__ __launch_bounds__(256) void gemm_v5f(
    const unsigned short* __restrict__ X, int ldx,
    const float* __restrict__ W, int ldw, int N,
    unsigned short* __restrict__ C, long long slotStride)
{
  __shared__ short8 lds[3584];
  const int tid = threadIdx.x;
  const int lane = tid & 63, wv = tid >> 6;
  const int l16 = lane & 15, kg = (lane >> 4) * 8;
  const int mbase = blockIdx.y * 112;
  const int ncol = blockIdx.x * 64 + wv * 16 + l16;
  const int nrow = (ncol < N) ? ncol : (N - 1);
  const long long k0 = (long long)blockIdx.z * (NKC * 256);
  C += (long long)blockIdx.z * slotStride;

  const float* wp = W + (size_t)nrow * ldw + kg + k0;
  const unsigned short* xb = X + (size_t)(mbase + l16) * ldx + kg + k0;
  const size_t xrow = (size_t)16 * ldx;

  f32x4 acc[7];
#pragma unroll
  for (int i = 0; i < 7; ++i) acc[i] = (f32x4){0.f, 0.f, 0.f, 0.f};

  for (int kc = 0; kc < NKC; ++kc) {
    if (kc) __syncthreads();
    float4 wa[8], wb[8];
#pragma unroll
    for (int ks = 0; ks < 8; ++ks) {
      wa[ks] = *(const float4*)(wp + kc * 256 + ks * 32);
      wb[ks] = *(const float4*)(wp + kc * 256 + ks * 32 + 4);
    }
    short8 xst[14];
#pragma unroll
    for (int i = 0; i < 14; ++i) {
      const int f = wv + i * 4, mt = f >> 3, ks = f & 7;
      xst[i] = *(const short8*)(xb + (size_t)mt * xrow + kc * 256 + ks * 32);
    }
#pragma unroll
    for (int i = 0; i < 14; ++i) lds[(wv + i * 4) * 64 + lane] = xst[i];
    __syncthreads();
#pragma unroll
    for (int ks = 0; ks < 8; ++ks) {
      short8 w;
      w[0] = (short)f2bf(wa[ks].x); w[1] = (short)f2bf(wa[ks].y);
      w[2] = (short)f2bf(wa[ks].z); w[3] = (short)f2bf(wa[ks].w);
      w[4] = (short)f2bf(wb[ks].x); w[5] = (short)f2bf(wb[ks].y);
      w[6] = (short)f2bf(wb[ks].z); w[7] = (short)f2bf(wb[ks].w);
#pragma unroll
      for (int mt = 0; mt < 7; ++mt) {
        short8 a = lds[(mt * 8 + ks) * 64 + lane];
        acc[mt] = __builtin_amdgcn_mfma_f32_16x16x32_bf16(a, w, acc[mt], 0, 0, 0);
      }
    }
  }
  if (ncol < N) {
    const int r0 = (lane >> 4) * 4;
#pragma unroll
    for (int mt = 0; mt < 7; ++mt)
#pragma unroll
      for (int r = 0; r < 4; ++r)
        C[(size_t)(mbase + mt * 16 + r0 + r) * N + ncol] = f2bf(acc[mt][r]);
  }
}

// ------------------- single fused weight pack (one dispatch) ----------------
__global__ __launch_bounds__(256) void k_pack_all(
    const float* __restrict__ Wih1, const float* __restrict__ Whh1,
    const float* __restrict__ Wih2, const float* __restrict__ Whh2,
    const float* __restrict__ Wfc1, const float* __restrict__ Wdec,
    const float* __restrict__ Wfc,  const float* __restrict__ Wlt,
    const float* __restrict__ Wft,  const float* __restrict__ Wtop,
    unsigned short* __restrict__ Wg1, unsigned short* __restrict__ Wg2,
    unsigned short* __restrict__ Wcat, unsigned short* __restrict__ Wfcb,
    unsigned short* __restrict__ Wltb, unsigned short* __restrict__ Wftb,
    unsigned short* __restrict__ Wtopb)
{
  int i = blockIdx.x * 256 + threadIdx.x;            // 15,278,080 vec4 total
  float4 v; unsigned short* dst; long long di;
  if (i < 2097152) {                                  // Wg1 = [Wih1.h2 | Whh1]
    int row = i >> 9, c4 = i & 511;
    const float* s = (c4 < 256) ? Wih1 + (size_t)row * 6144 + c4 * 4
                                : Whh1 + (size_t)row * 1024 + (c4 - 256) * 4;
    v = *(const float4*)s; dst = Wg1; di = i;
  } else if (i < 8388608) {                           // Wg2 = [Wih2 | Whh2]
    int j = i - 2097152; int row = j / 1536, c4 = j - row * 1536;
    const float* s = (c4 < 1280) ? Wih2 + (size_t)row * 5120 + c4 * 4
                                 : Whh2 + (size_t)row * 1024 + (c4 - 1280) * 4;
    v = *(const float4*)s; dst = Wg2; di = j;
  } else if (i < 11079680) {                          // Wcat = [W_fc1 ; W_dec]
    int j = i - 8388608; int row = j >> 8, c4 = j & 255;
    const float* s = (row < 10000) ? Wfc1 + (size_t)row * 1024 + c4 * 4
                                   : Wdec + (size_t)(row - 10000) * 1024 + c4 * 4;
    v = *(const float4*)s; dst = Wcat; di = j;
  } else if (i < 13639680) { int j = i - 11079680; v = ((const float4*)Wfc)[j]; dst = Wfcb; di = j; }
  else if (i < 14688256) { int j = i - 13639680; v = ((const float4*)Wlt)[j]; dst = Wltb; di = j; }
  else if (i < 15212544) { int j = i - 14688256; v = ((const float4*)Wft)[j]; dst = Wftb; di = j; }
  else {                                              // Wtopb 512x512, K-pad 500->512
    int j = i - 15212544; int n = j >> 7, c4 = j & 127;
    v = (c4 < 125) ? *(const float4*)(Wtop + (size_t)n * 500 + c4 * 4)
                   : (float4){0.f, 0.f, 0.f, 0.f};
    dst = Wtopb; di = j;
  }
  short4v o; o[0] = (short)f2bf(v.x); o[1] = (short)f2bf(v.y);
  o[2] = (short)f2bf(v.z); o[3] = (short)f2bf(v.w);
  ((short4v*)dst)[di] = o;
}

// --------------------------- phase-A helper kernels ------------------------
__global__ __launch_bounds__(256) void k_ximg(const float* __restrict__ src,
                                              unsigned short* __restrict__ dst) {
  int idx = blockIdx.x * 256 + threadIdx.x;          // 1568*4096
  int row = idx >> 12;
  dst[idx] = (row < 1500) ? f2bf(src[idx]) : (unsigned short)0;
}

__global__ __launch_bounds__(256) void k_mean(const float* __restrict__ img,
                                              unsigned short* __restrict__ dst) {
  int idx = blockIdx.x * 256 + threadIdx.x;          // 112*4096
  int b = idx >> 12, f = idx & 4095;
  unsigned short r = 0;
  if (b < 100) {
    float s = 0.f;
    for (int rr = 0; rr < 15; ++rr) s += img[((size_t)b * 15 + rr) * 4096 + f];
    r = f2bf(s * (1.f / 15.f));
  }
  dst[idx] = r;
}

__global__ __launch_bounds__(256) void k_reduce(const unsigned short* __restrict__ P,
    long long ss, int nslots, const float* __restrict__ bias, int colmask,
    float* __restrict__ out, int total) {
  int idx = blockIdx.x * 256 + threadIdx.x;
  if (idx >= total) return;
  float s = bias ? bias[idx & colmask] : 0.f;
  for (int sl = 0; sl < nslots; ++sl) s += bf2f(P[(size_t)sl * ss + idx]);
  out[idx] = s;
}

// conv with the split-K reduce of `lin` fused in (reads bf16 partials)
__global__ __launch_bounds__(512) void k_conv(const unsigned short* __restrict__ px,
    const float* __restrict__ blt, const float* __restrict__ cw,
    const float* __restrict__ cb, float* __restrict__ topics) {
  int b = blockIdx.x;
  __shared__ float L[15 * 1024];
  for (int i = threadIdx.x; i < 15 * 1024; i += 512) {
    float s = blt[i & 1023];
#pragma unroll
    for (int sl = 0; sl < 4; ++sl)
      s += bf2f(px[(size_t)sl * 1605632 + (size_t)b * 15360 + i]);
    L[i] = s;
  }
  __syncthreads();
  for (int idx = threadIdx.x; idx < 2500; idx += 512) {
    int tt = idx / 500, w = idx - tt * 500;
    float s = cb[tt];
    for (int kh = 0; kh < 15; ++kh) {
      const float* lr = &L[kh * 1024 + 2 * w];
      const float* wr = &cw[(tt * 15 + kh) * 26];
#pragma unroll
      for (int kw = 0; kw < 26; ++kw) s += lr[kw] * wr[kw];
    }
    topics[(size_t)b * 2500 + idx] = s;
  }
}

__global__ __launch_bounds__(256) void k_padtop(const float* __restrict__ topics,
    unsigned short* __restrict__ Xtop) {
  int idx = blockIdx.x * 256 + threadIdx.x;          // 560*512
  if (idx >= 560 * 512) return;
  int r = idx >> 9, k = idx & 511;
  Xtop[idx] = (r < 500 && k < 500) ? f2bf(topics[(size_t)r * 500 + k]) : (unsigned short)0;
}

__global__ void k_wc(const int* __restrict__ caps, const int* __restrict__ lens,
                     int* __restrict__ words, float* __restrict__ out2,
                     float* __restrict__ out3) {
  int idx = blockIdx.x * 256 + threadIdx.x;
  if (idx < 26000) out2[idx] = (float)caps[idx];
  if (idx < 500) {
    int len = lens[idx];
    words[idx] = caps[idx * 52 + len - 1];
    out3[idx] = (float)(len - 1);
  }
}

__global__ __launch_bounds__(256) void k_gather(const float* __restrict__ emb,
    const int* __restrict__ words, unsigned short* __restrict__ Xemb) {
  int idx = blockIdx.x * 256 + threadIdx.x;          // 560*1024
  int bt = idx >> 10, e = idx & 1023;
  Xemb[idx] = (bt < 500) ? f2bf(emb[(size_t)words[bt] * 1024 + e]) : (unsigned short)0;
}

__global__ __launch_bounds__(256) void k_gbase1(const unsigned short* __restrict__ P,
    const float* __restrict__ bih, const float* __restrict__ bhh,
    float* __restrict__ gb) {
  int idx = blockIdx.x * 256 + threadIdx.x;          // 112*4096
  int m = idx >> 12, n = idx & 4095;
  float s = bih[n] + bhh[n];
#pragma unroll
  for (int sl = 0; sl < 8; ++sl) s += bf2f(P[((size_t)sl * 112 + m) * 4096 + n]);
  gb[idx] = s;
}

// ------------------------------ per-step kernels ---------------------------
__global__ __launch_bounds__(256) void k_lstm1(const unsigned short* __restrict__ P,
    const float* __restrict__ gb1, const float* __restrict__ gemb, int t,
    float* __restrict__ c1, unsigned short* __restrict__ Xh1,
    unsigned short* __restrict__ X1, unsigned short* __restrict__ X2) {
  int idx = blockIdx.x * 256 + threadIdx.x;          // 100*1024
  int b = idx >> 10, j = idx & 1023;
  float g[4];
#pragma unroll
  for (int x = 0; x < 4; ++x) {
    int col = (x << 10) + j;
    float s = gb1[b * 4096 + col] + gemb[((size_t)b * 5 + t) * 4096 + col];
#pragma unroll
    for (int sl = 0; sl < 8; ++sl) s += bf2f(P[((size_t)sl * 112 + b) * 4096 + col]);
    g[x] = s;
  }
  float c = sigm(g[1]) * c1[idx] + sigm(g[0]) * tanhf(g[2]);
  float h = sigm(g[3]) * tanhf(c);
  c1[idx] = c;
  unsigned short hb = f2bf(h);
  Xh1[idx] = hb;
  X1[b * 2048 + 1024 + j] = hb;
  X2[(size_t)b * 6144 + 4096 + j] = hb;
}

// fused attention scores + softmax + awe (one block per batch element)
__global__ __launch_bounds__(256) void k_attawe(const float* __restrict__ att1,
    const unsigned short* __restrict__ padec, const float* __restrict__ bdec,
    const float* __restrict__ btop, const unsigned short* __restrict__ ttopb,
    const float* __restrict__ wfull, int t,
    const unsigned short* __restrict__ Ximg, unsigned short* __restrict__ X2) {
  int b = blockIdx.x;
  int tid = threadIdx.x;
  int r = tid & 15, ch = tid >> 4;                   // 15 regions x 16 chunks of 32n
  __shared__ float sp[16][17];
  __shared__ float al[16];
  float s = 0.f;
  if (r < 15) {
    const float* a1 = att1 + ((size_t)b * 15 + r) * 512;
    const unsigned short* tp = ttopb + ((size_t)b * 5 + t) * 512;
#pragma unroll
    for (int j = 0; j < 32; ++j) {
      int n = ch * 32 + j;
      float ad = bdec[n] + btop[n]
               + bf2f(padec[((size_t)0 * 112 + b) * 10512 + 10000 + n])
               + bf2f(padec[((size_t)1 * 112 + b) * 10512 + 10000 + n])
               + bf2f(padec[((size_t)2 * 112 + b) * 10512 + 10000 + n])
               + bf2f(padec[((size_t)3 * 112 + b) * 10512 + 10000 + n]);
      float v = a1[n] + ad + bf2f(tp[n]);
      s += fmaxf(v, 0.f) * wfull[n];
    }
  }
  sp[r][ch] = s;
  __syncthreads();
  if (tid == 0) {
    float sc[15];
    float m = -1e30f;
    for (int rr = 0; rr < 15; ++rr) {
      float x = 0.f;
      for (int cc = 0; cc < 16; ++cc) x += sp[rr][cc];
      sc[rr] = x; m = fmaxf(m, x);
    }
    float sum = 0.f;
    for (int rr = 0; rr < 15; ++rr) { sc[rr] = expf(sc[rr] - m); sum += sc[rr]; }
    float inv = 1.f / sum;
    for (int rr = 0; rr < 15; ++rr) al[rr] = sc[rr] * inv;
  }
  __syncthreads();
  for (int f = tid; f < 4096; f += 256) {
    float s2 = 0.f;
#pragma unroll
    for (int rr = 0; rr < 15; ++rr)
      s2 += al[rr] * bf2f(Ximg[((size_t)b * 15 + rr) * 4096 + f]);
    X2[(size_t)b * 6144 + f] = f2bf(s2);
  }
}

__global__ __launch_bounds__(256) void k_lstm2(const unsigned short* __restrict__ P,
    const float* __restrict__ bih, const float* __restrict__ bhh,
    float* __restrict__ c2, unsigned short* __restrict__ Xh2,
    unsigned short* __restrict__ X1, unsigned short* __restrict__ X2) {
  int idx = blockIdx.x * 256 + threadIdx.x;          // 100*1024
  int b = idx >> 10, j = idx & 1023;
  float g[4];
#pragma unroll
  for (int x = 0; x < 4; ++x) {
    int col = (x << 10) + j;
    float s = bih[col] + bhh[col];
#pragma unroll
    for (int sl = 0; sl < 12; ++sl) s += bf2f(P[((size_t)sl * 112 + b) * 4096 + col]);
    g[x] = s;
  }
  float c = sigm(g[1]) * c2[idx] + sigm(g[0]) * tanhf(g[2]);
  float h = sigm(g[3]) * tanhf(c);
  c2[idx] = c;
  unsigned short hb = f2bf(h);
  Xh2[idx] = hb;
  X1[b * 2048 + j] = hb;
  X2[(size_t)b * 6144 + 5120 + j] = hb;
}

__global__ __launch_bounds__(256) void k_eppred(const unsigned short* __restrict__ P,
    const float* __restrict__ bias, float* __restrict__ outp, int t, int ldp) {
  int idx = blockIdx.x * 256 + threadIdx.x;          // 100*10000
  if (idx >= 1000000) return;
  int b = idx / 10000, v = idx - b * 10000;
  outp[((size_t)b * 5 + t) * 10000 + v] = bias[v]
      + bf2f(P[(size_t)(0 * 112 + b) * ldp + v]) + bf2f(P[(size_t)(112 + b) * ldp + v])
      + bf2f(P[(size_t)(224 + b) * ldp + v])     + bf2f(P[(size_t)(336 + b) * ldp + v]);
}

// ---------------------------------------------------------------------------
extern "C" void kernel_launch(void* const* d_in, const int* in_sizes, int n_in,
                              void* d_out, int out_size, void* d_ws, size_t ws_size,
                              hipStream_t stream) {
  (void)in_sizes; (void)n_in; (void)out_size;
  const float* imgf  = (const float*)d_in[0];
  const int*   caps  = (const int*)d_in[1];
  const int*   lens  = (const int*)d_in[2];
  const float* W_lt  = (const float*)d_in[3];
  const float* b_lt  = (const float*)d_in[4];
  const float* convw = (const float*)d_in[5];
  const float* convb = (const float*)d_in[6];
  const float* W_feat = (const float*)d_in[7];
  const float* b_feat = (const float*)d_in[8];
  const float* W_dec = (const float*)d_in[9];
  const float* b_dec = (const float*)d_in[10];
  const float* W_top = (const float*)d_in[11];
  const float* b_top = (const float*)d_in[12];
  const float* W_full = (const float*)d_in[13];
  const float* b_full = (const float*)d_in[14];  (void)b_full;  // cancels in softmax
  const float* emb   = (const float*)d_in[15];
  const float* W_ih1 = (const float*)d_in[16];
  const float* W_hh1 = (const float*)d_in[17];
  const float* b_ih1 = (const float*)d_in[18];
  const float* b_hh1 = (const float*)d_in[19];
  const float* W_ih2 = (const float*)d_in[20];
  const float* W_hh2 = (const float*)d_in[21];
  const float* b_ih2 = (const float*)d_in[22];
  const float* b_hh2 = (const float*)d_in[23];
  const float* W_fc1 = (const float*)d_in[24];
  const float* b_fc1 = (const float*)d_in[25];
  const float* W_fc  = (const float*)d_in[26];
  const float* b_fc  = (const float*)d_in[27];
  float* out = (float*)d_out;

  char* ws = (char*)d_ws;
  size_t off = 0;
  auto alloc = [&](size_t bytes) -> size_t {
    size_t o = off; off = (off + bytes + 255) & ~(size_t)255; return o;
  };
  const size_t oXimg  = alloc(1568ull * 4096 * 2);
  const size_t oXmean = alloc(112ull * 4096 * 2);
  const size_t oXemb  = alloc(560ull * 1024 * 2);
  const size_t oZERO  = off;                         // ---- zero block start
  const size_t oX1    = alloc(112ull * 2048 * 2);    // [h2 | h1] bf16
  const size_t oX2    = alloc(112ull * 6144 * 2);    // [awe | h1 | h2prev] bf16
  const size_t oXh1   = alloc(112ull * 1024 * 2);
  const size_t oXh2   = alloc(112ull * 1024 * 2);
  const size_t oc1    = alloc(100ull * 1024 * 4);
  const size_t oc2    = alloc(100ull * 1024 * 4);
  const size_t zeroBytes = off - oZERO;              // ---- zero block end
  const size_t otop   = alloc(100ull * 2500 * 4);
  const size_t oXtop  = alloc(560ull * 512 * 2);
  const size_t oTtopb = alloc(560ull * 512 * 2);
  const size_t oatt1  = alloc(1568ull * 512 * 4);
  const size_t ogb1   = alloc(112ull * 4096 * 4);
  const size_t ogemb  = alloc(560ull * 4096 * 4);
  const size_t owords = alloc(512ull * 4);
  const size_t opg    = alloc(12ull * 112 * 4096 * 2);  // gate partials (bf16)
  const size_t opx    = alloc(4ull * 560 * 4096 * 2);   // shared partials (bf16), 18.4 MB
  const size_t oWg1   = alloc(4096ull * 2048 * 2);      // [Wih1.h2 | Whh1]
  const size_t oWg2   = alloc(4096ull * 6144 * 2);      // [Wih2 | Whh2]
  const size_t oWcat  = alloc(10512ull * 1024 * 2);     // [W_fc1 ; W_dec]
  const size_t oWfcb  = alloc(10000ull * 1024 * 2);
  const size_t oWltb  = alloc(1024ull * 4096 * 2);
  const size_t oWftb  = alloc(512ull * 4096 * 2);
  const size_t oWtopb = alloc(512ull * 512 * 2);
  if (ws_size < off) return;  // insufficient scratch — loud fail

  unsigned short* Ximg  = (unsigned short*)(ws + oXimg);
  unsigned short* Xmean = (unsigned short*)(ws + oXmean);
  unsigned short* Xemb  = (unsigned short*)(ws + oXemb);
  unsigned short* X1    = (unsigned short*)(ws + oX1);
  unsigned short* X2    = (unsigned short*)(ws + oX2);
  unsigned short* Xh1   = (unsigned short*)(ws + oXh1);
  unsigned short* Xh2   = (unsigned short*)(ws + oXh2);
  float* c1    = (float*)(ws + oc1);
  float* c2    = (float*)(ws + oc2);
  float* topics = (float*)(ws + otop);
  unsigned short* Xtop  = (unsigned short*)(ws + oXtop);
  unsigned short* Ttopb = (unsigned short*)(ws + oTtopb);
  float* att1  = (float*)(ws + oatt1);
  float* gb1   = (float*)(ws + ogb1);
  float* gemb  = (float*)(ws + ogemb);
  int*   words = (int*)(ws + owords);
  unsigned short* pg = (unsigned short*)(ws + opg);
  unsigned short* px = (unsigned short*)(ws + opx);
  unsigned short* Wg1   = (unsigned short*)(ws + oWg1);
  unsigned short* Wg2   = (unsigned short*)(ws + oWg2);
  unsigned short* Wcat  = (unsigned short*)(ws + oWcat);
  unsigned short* Wfcb  = (unsigned short*)(ws + oWfcb);
  unsigned short* Wltb  = (unsigned short*)(ws + oWltb);
  unsigned short* Wftb  = (unsigned short*)(ws + oWftb);
  unsigned short* Wtopb = (unsigned short*)(ws + oWtopb);

  const long long S4  = 112ll * 4096;    // gate partial slot stride
  const long long SP1 = 112ll * 10512;   // cat (preds1+adec) partial slot stride
  const long long SP  = 112ll * 10000;   // preds partial slot stride

  hipMemsetAsync(ws + oZERO, 0, zeroBytes, stream);

  // -------- phase A (once) --------
  k_ximg<<<25088, 256, 0, stream>>>(imgf, Ximg);
  k_mean<<<1792, 256, 0, stream>>>(imgf, Xmean);
  k_pack_all<<<59680, 256, 0, stream>>>(W_ih1, W_hh1, W_ih2, W_hh2, W_fc1, W_dec,
                                        W_fc, W_lt, W_feat, W_top,
                                        Wg1, Wg2, Wcat, Wfcb, Wltb, Wftb, Wtopb);
  // autoencoder linear: K=4096 = 4z * 1024
  gemm_v5<4><<<dim3(16, 14, 4), 256, 0, stream>>>(Ximg, 4096, Wltb, 4096, 1024,
                                                  px, 1568ll * 1024);
  k_conv<<<100, 512, 0, stream>>>(px, b_lt, convw, convb, topics);
  k_padtop<<<1120, 256, 0, stream>>>(topics, Xtop);
  // ttop = topics @ W_top^T (padded K=512), bf16 out, single z
  gemm_v5<2><<<dim3(8, 5, 1), 256, 0, stream>>>(Xtop, 512, Wtopb, 512, 512, Ttopb, 0);
  // att1: K=4096 = 4z * 1024
  gemm_v5<4><<<dim3(8, 14, 4), 256, 0, stream>>>(Ximg, 4096, Wftb, 4096, 512,
                                                 px, 1568ll * 512);
  k_reduce<<<3136, 256, 0, stream>>>(px, 1568ll * 512, 4, b_feat, 511, att1, 1568 * 512);
  k_wc<<<102, 256, 0, stream>>>(caps, lens, words, out + 10000000, out + 10026000);
  k_gather<<<2240, 256, 0, stream>>>(emb, words, Xemb);
  // img_mean panel of W_ih1 (f32, one-time): K=4096 = 8z * 512
  gemm_v5f<2><<<dim3(64, 1, 8), 256, 0, stream>>>(Xmean, 4096, W_ih1 + 1024, 6144, 4096,
                                                  pg, S4);
  k_gbase1<<<1792, 256, 0, stream>>>(pg, b_ih1, b_hh1, gb1);
  // emb panel of W_ih1 (f32, one-time): all 5 steps, K=1024 = 4z * 256
  gemm_v5f<1><<<dim3(64, 5, 4), 256, 0, stream>>>(Xemb, 1024, W_ih1 + 5120, 6144, 4096,
                                                  px, 560ll * 4096);
  k_reduce<<<8960, 256, 0, stream>>>(px, 560ll * 4096, 4, nullptr, 4095, gemb, 560 * 4096);

  // -------- recurrent steps --------
  for (int t = 0; t < 5; ++t) {
    // gates1 = Wg1 @ [h2|h1prev]: K=2048 = 8z * 256
    gemm_v5<1><<<dim3(64, 1, 8), 256, 0, stream>>>(X1, 2048, Wg1, 2048, 4096, pg, S4);
    k_lstm1<<<400, 256, 0, stream>>>(pg, gb1, gemb, t, c1, Xh1, X1, X2);
    // [preds1 | adec] = Xh1 @ Wcat^T: N=10512, K=1024 = 4z * 256
    gemm_v5<1><<<dim3(165, 1, 4), 256, 0, stream>>>(Xh1, 1024, Wcat, 1024, 10512, px, SP1);
    k_attawe<<<100, 256, 0, stream>>>(att1, px, b_dec, b_top, Ttopb, W_full, t, Ximg, X2);
    k_eppred<<<3907, 256, 0, stream>>>(px, b_fc1, out + 5000000, t, 10512);
    // gates2 = Wg2 @ [awe|h1|h2prev]: K=6144 = 12z * 512
    gemm_v5<2><<<dim3(64, 1, 12), 256, 0, stream>>>(X2, 6144, Wg2, 6144, 4096, pg, S4);
    k_lstm2<<<400, 256, 0, stream>>>(pg, b_ih2, b_hh2, c2, Xh2, X1, X2);
    // preds = Xh2 @ W_fc^T: K=1024 = 4z * 256
    gemm_v5<1><<<dim3(157, 1, 4), 256, 0, stream>>>(Xh2, 1024, Wfcb, 1024, 10000, px, SP);
    k_eppred<<<3907, 256, 0, stream>>>(px, b_fc, out, t, 10000);
  }
}